// Round 5
// baseline (4428.005 us; speedup 1.0000x reference)
//
#include <hip/hip_runtime.h>
#include <math.h>

#define LSEQ 2048
#define NB 8
#define NCH 64
#define NTOT (NB*NCH*LSEQ)   // 1048576
#define NROWS (NB*NCH)       // 512
#define TP 32                // ode eval tile (positions per block)

__device__ __forceinline__ float geluf(float x){
    return 0.5f*x*(1.0f+erff(x*0.70710678118654752f));
}
__device__ __forceinline__ float siluf(float x){
    return x/(1.0f+expf(-x));
}
__device__ __forceinline__ float sigf(float x){
    return 1.0f/(1.0f+expf(-x));
}

// ---------------- weight transpose: w[64][64][3] -> wt[192][64] --------------
__global__ __launch_bounds__(256) void wtrans_kernel(const float* __restrict__ w,
                                                     float* __restrict__ wt){
    int idx = blockIdx.x*256 + threadIdx.x;   // 12288 total
    int j = idx >> 6, co = idx & 63;
    wt[idx] = w[co*192 + j];
}

// ---------------- stat = mean over L ----------------------------------------
__global__ __launch_bounds__(256) void stat_kernel(const float* __restrict__ in,
                                                   float* __restrict__ stat){
    int r = blockIdx.x, tid = threadIdx.x;
    const float* p = in + (size_t)r*LSEQ;
    float acc = 0.f;
    for (int i=tid;i<LSEQ;i+=256) acc += p[i];
    for (int o=32;o>0;o>>=1) acc += __shfl_down(acc,o,64);
    __shared__ float red[4];
    if ((tid&63)==0) red[tid>>6]=acc;
    __syncthreads();
    if (tid==0) stat[r] = (red[0]+red[1]+red[2]+red[3])*(1.0f/LSEQ);
}

// ---------------- dywan MLP + filters + ortho -------------------------------
__global__ __launch_bounds__(256) void dywan_kernel(
    const float* __restrict__ stat,
    const float* __restrict__ w1, const float* __restrict__ b1,
    const float* __restrict__ wg1, const float* __restrict__ bg1,
    const float* __restrict__ wg2, const float* __restrict__ bg2,
    float* __restrict__ lo_out, float* __restrict__ hi_out,
    float* __restrict__ ortho_out)
{
    __shared__ float st[512];
    __shared__ float h1s[512];
    __shared__ float h2s[1024];
    __shared__ float fs[112];
    int tid = threadIdx.x;
    for (int i=tid;i<512;i+=256) st[i]=stat[i];
    __syncthreads();
    for (int idx=tid; idx<512; idx+=256){
        int b=idx>>6, j=idx&63;
        float acc=b1[j];
        const float* W=w1+j*64;
        for (int i=0;i<64;i++) acc += st[b*64+i]*W[i];
        h1s[idx]=geluf(acc);
    }
    __syncthreads();
    for (int idx=tid; idx<1024; idx+=256){
        int b=idx>>7, j=idx&127;
        float acc=bg1[j];
        const float* W=wg1+j*64;
        for (int i=0;i<64;i++) acc += h1s[b*64+i]*W[i];
        h2s[idx]=geluf(acc);
    }
    __syncthreads();
    if (tid<112){
        int b=tid/14, j=tid-b*14;
        float acc=bg2[j];
        const float* W=wg2+j*128;
        for (int i=0;i<128;i++) acc += h2s[b*128+i]*W[i];
        fs[tid]=acc;
    }
    __syncthreads();
    if (tid<56){
        int b=tid/7, k=tid-b*7;
        lo_out[tid]=fs[b*14+k];
        hi_out[tid]=fs[b*14+7+k];
    }
    if (tid==0){
        float smooth=0.f, shiftsum=0.f, ampsum=0.f;
        for (int b=0;b<8;b++){
            const float* l = fs + b*14;   // lo row
            float prev=0.f, nrm=0.f;
            for (int k=0;k<7;k++){ smooth += fabsf(l[k]-prev); prev=l[k]; nrm += l[k]*l[k]; }
            smooth += fabsf(prev);
            float denom = sqrtf(nrm) + 1e-8f;
            float sabs=0.f, s2=0.f;
            for (int k=0;k<7;k++){ float v=l[k]/denom; sabs+=fabsf(v); s2+=v*v; }
            shiftsum += sabs*sabs;
            ampsum += fabsf(s2-1.0f);
        }
        smooth *= (1.0f/64.0f);
        float shift = 3.0f*shiftsum/(8.0f*49.0f);
        float amp = ampsum*(1.0f/8.0f);
        *ortho_out = 0.01f*(shift+amp) + 0.1f*smooth;
    }
}

// ---------------- per-batch 7-tap filter conv (edge pad) --------------------
__global__ __launch_bounds__(256) void filt_kernel(
    const float* __restrict__ ap, const float* __restrict__ lo,
    const float* __restrict__ hi, float* __restrict__ na,
    float* __restrict__ det)
{
    int r = blockIdx.y, l0 = blockIdx.x*256, tid = threadIdx.x;
    int b = r>>6;
    __shared__ float s[262];
    __shared__ float fl[7], fh[7];
    for (int idx=tid; idx<262; idx+=256){
        int l = l0+idx-3;
        l = min(max(l,0),LSEQ-1);
        s[idx]=ap[(size_t)r*LSEQ+l];
    }
    if (tid<7) fl[tid]=lo[b*7+tid];
    else if (tid<14) fh[tid-7]=hi[b*7+tid-7];
    __syncthreads();
    float a=0.f, d=0.f;
    #pragma unroll
    for (int k=0;k<7;k++){ float v=s[tid+k]; a+=v*fl[k]; d+=v*fh[k]; }
    na[(size_t)r*LSEQ+l0+tid]=a;
    det[(size_t)r*LSEQ+l0+tid]=d;
}

// ---------------- time grid pass1: per-row stats (batched over levels) ------
__global__ __launch_bounds__(256) void tg_pass1(const float* __restrict__ CB,
                                                float* __restrict__ rowstats){
    __shared__ float sh[2048];
    __shared__ float red[28];
    int r = blockIdx.x, lvl = blockIdx.y, tid = threadIdx.x;
    const float* s = CB + (size_t)lvl*NTOT + (size_t)r*LSEQ;
    float* rso = rowstats + (size_t)(lvl*NROWS+r)*8;
    for (int i=tid;i<2048;i+=256) sh[i]=s[i];
    __syncthreads();
    float ssq=0.f;
    for (int i=tid;i<2048;i+=256){ float v=sh[i]; ssq+=v*v; }
    float mn=1e30f, mx=-1e30f, s0=0.f,s1=0.f,s2=0.f,s3=0.f;
    for (int j=tid;j<2047;j+=256){
        int k0 = (j-2>0)? j-2:0;
        int k1 = (j+2<2046)? j+2:2046;
        float acc=0.f;
        for (int k=k0;k<=k1;k++) acc += fabsf(sh[k+1]-sh[k]);
        float inten = acc*0.2f;
        mn=fminf(mn,inten); mx=fmaxf(mx,inten);
        if (j<511)  s0+=inten;
        if (j<1023) s1+=inten;
        if (j<1534) s2+=inten;
        if (j<2046) s3+=inten;
    }
    float vals[7]={mn,mx,s0,s1,s2,s3,ssq};
    for (int o=32;o>0;o>>=1){
        vals[0]=fminf(vals[0],__shfl_down(vals[0],o,64));
        vals[1]=fmaxf(vals[1],__shfl_down(vals[1],o,64));
        vals[2]+=__shfl_down(vals[2],o,64);
        vals[3]+=__shfl_down(vals[3],o,64);
        vals[4]+=__shfl_down(vals[4],o,64);
        vals[5]+=__shfl_down(vals[5],o,64);
        vals[6]+=__shfl_down(vals[6],o,64);
    }
    int lane=tid&63, w=tid>>6;
    if (lane==0) for (int q=0;q<7;q++) red[w*7+q]=vals[q];
    __syncthreads();
    if (tid==0){
        rso[0]=fminf(fminf(red[0],red[7]),fminf(red[14],red[21]));
        rso[1]=fmaxf(fmaxf(red[1],red[8]),fmaxf(red[15],red[22]));
        rso[2]=red[2]+red[9]+red[16]+red[23];
        rso[3]=red[3]+red[10]+red[17]+red[24];
        rso[4]=red[4]+red[11]+red[18]+red[25];
        rso[5]=red[5]+red[12]+red[19]+red[26];
        rso[6]=red[6]+red[13]+red[20]+red[27];
    }
}

// ---------------- time grid finalize + modulation (grid = 4 levels) ---------
__global__ __launch_bounds__(256) void tg_finalize(
    const float* __restrict__ rowstats,
    const float* __restrict__ wt, const float* __restrict__ bt,
    const float* __restrict__ wm, const float* __restrict__ bm,
    const float* __restrict__ emb,
    float* __restrict__ ts_out, float* __restrict__ modsc,
    float* __restrict__ modbi, float* __restrict__ ein,
    float* __restrict__ eout)
{
    int tid=threadIdx.x;
    const int lvl=blockIdx.x;
    const float* rs = rowstats + (size_t)lvl*NROWS*8;
    __shared__ float red[28];
    __shared__ float stv[9];
    __shared__ float temb[144];
    float mn=1e30f,mx=-1e30f,a0=0.f,a1=0.f,a2=0.f,a3=0.f,m3=-1e30f;
    for (int r=tid;r<512;r+=256){
        mn=fminf(mn,rs[r*8+0]); mx=fmaxf(mx,rs[r*8+1]);
        a0+=rs[r*8+2]; a1+=rs[r*8+3]; a2+=rs[r*8+4]; a3+=rs[r*8+5];
        m3=fmaxf(m3,rs[r*8+5]);
    }
    float vals[7]={mn,mx,a0,a1,a2,a3,m3};
    for (int o=32;o>0;o>>=1){
        vals[0]=fminf(vals[0],__shfl_down(vals[0],o,64));
        vals[1]=fmaxf(vals[1],__shfl_down(vals[1],o,64));
        vals[2]+=__shfl_down(vals[2],o,64);
        vals[3]+=__shfl_down(vals[3],o,64);
        vals[4]+=__shfl_down(vals[4],o,64);
        vals[5]+=__shfl_down(vals[5],o,64);
        vals[6]=fmaxf(vals[6],__shfl_down(vals[6],o,64));
    }
    int lane=tid&63, w=tid>>6;
    if (lane==0) for (int q=0;q<7;q++) red[w*7+q]=vals[q];
    if (tid<8){
        float e=0.f;
        for (int c=0;c<64;c++) e += rs[(tid*64+c)*8+6];
        ein[lvl*8+tid]=e*(1.0f/131072.0f);
        eout[lvl*8+tid]=0.f;
    }
    __syncthreads();
    if (tid==0){
        float mnv=fminf(fminf(red[0],red[7]),fminf(red[14],red[21]));
        float mxv=fmaxf(fmaxf(red[1],red[8]),fmaxf(red[15],red[22]));
        float s0=red[2]+red[9]+red[16]+red[23];
        float s1=red[3]+red[10]+red[17]+red[24];
        float s2=red[4]+red[11]+red[18]+red[25];
        float s3=red[5]+red[12]+red[19]+red[26];
        float m3v=fmaxf(fmaxf(red[6],red[13]),fmaxf(red[20],red[27]));
        const float idxs[5]={0.f,511.f,1023.f,1534.f,2046.f};
        float tsv[5];
        if (mxv-mnv < 1e-8f){
            for (int k=0;k<5;k++) tsv[k]=idxs[k]/2046.0f;
        } else {
            float a = 0.9f/(mxv-mnv+1e-30f);
            float bb = 0.1f - a*mnv;
            float gmax = a*m3v + bb*2046.0f;
            float sums[5]={0.f,s0,s1,s2,s3};
            tsv[0]=0.f;
            for (int k=1;k<5;k++)
                tsv[k]=(a*(sums[k]*(1.0f/512.0f)) + bb*idxs[k])/gmax;
        }
        for (int k=0;k<5;k++){ ts_out[lvl*8+k]=tsv[k]; stv[2*k]=tsv[k]; }
        for (int k=0;k<4;k++) stv[2*k+1]=tsv[k] + 0.5f*(tsv[k+1]-tsv[k]);
    }
    __syncthreads();
    if (tid<144){
        int m=tid>>4, i=tid&15;
        float z = wt[lvl*16+i]*stv[m] + bt[lvl*16+i];
        temb[tid]=siluf(z);
    }
    __syncthreads();
    for (int idx=tid; idx<1152; idx+=256){
        int m=idx>>7, c=idx&127;
        float g=bm[lvl*128+c];
        const float* W=wm+(size_t)(lvl*128+c)*16;
        const float* te=temb+m*16;
        for (int i=0;i<16;i++) g += W[i]*te[i];
        if (c<64) modsc[lvl*576+m*64+c]=1.0f+g+emb[(lvl*8+lvl)*64+c];
        else      modbi[lvl*576+m*64+(c-64)]=g;
    }
}

// ---------------- fused ode_f eval, batched over levels, ci-split waves -----
// grid (64, 8, 4): (pos tile, batch, level). block 256 = 4 waves.
// Wave w owns ci-slice [w*16, w*16+16); lane = output channel co.
// Weights for the slice live in registers (48/stage); partial sums combined
// via LDS float atomics (nondeterministic add order: ~ulp noise only).
__global__ __launch_bounds__(256,4) void ode_eval_all(
    const float* __restrict__ yinB, const float* __restrict__ kprevB,
    float* __restrict__ koutB, float* __restrict__ accB,
    float* __restrict__ youtB,
    const float* __restrict__ wtB, const float* __restrict__ c1bB,
    const float* __restrict__ c2bB,
    const float* __restrict__ modscB, const float* __restrict__ modbiB,
    const float* __restrict__ tsB, float* __restrict__ eoutB,
    int step, int eval, int do_energy)
{
    __shared__ float ye[64][37];    // u in [0,36): l = l0-2+u
    __shared__ float hsum[64][35];  // v in [0,34): h pos = l0-1+v
    __shared__ float csum[64][33];  // p in [0,32)
    __shared__ float sb1[64], sb2[64];
    __shared__ float red[4];
    const int tid=threadIdx.x;
    const int lvl=blockIdx.z;
    const int b=blockIdx.y;
    const int l0=blockIdx.x*TP;
    const size_t loff=(size_t)lvl*NTOT;
    const float* yin = yinB + loff;
    const float* kprev = kprevB + loff;
    float* kout = koutB + loff;
    float* acc = accB + loff;
    float* yout = youtB + loff;
    const float* w1t = wtB + (size_t)lvl*24576;
    const float* w2t = w1t + 12288;
    const float dt = tsB[lvl*8+step+1]-tsB[lvl*8+step];
    const float alpha=(eval==0)?0.f:((eval==3)?dt:0.5f*dt);
    const int tslot=2*step+((eval==0)?0:((eval==3)?2:1));
    const int w=tid>>6, co=tid&63;
    const int ci0=w*16;

    // phase A: biases to LDS, fill ye (halo 2, zero-pad at seq ends)
    if (tid<64) sb1[tid]=c1bB[lvl*64+tid];
    else if (tid<128) sb2[tid-64]=c2bB[lvl*64+tid-64];
    for (int idx=tid; idx<64*36; idx+=256){
        int ci=idx/36, u=idx-ci*36;
        int l=l0+u-2;
        float v=0.f;
        if (l>=0 && l<LSEQ){
            size_t gi=(size_t)(b*64+ci)*LSEQ+l;
            v=yin[gi];
            if (eval!=0) v+=alpha*kprev[gi];
        }
        ye[ci][u]=v;
    }
    // preload stage-1 weights for this wave's ci slice (coalesced over co)
    float wr[48];
    {
        const float* wbase = w1t + co;
        #pragma unroll
        for (int t=0;t<16;t++){
            const float* wp = wbase + (ci0+t)*192;
            wr[t*3+0]=wp[0]; wr[t*3+1]=wp[64]; wr[t*3+2]=wp[128];
        }
    }
    __syncthreads();
    // phase B: init partial-sum arrays with biases
    for (int idx=tid; idx<64*34; idx+=256){
        int ci=idx/34, v=idx-ci*34;
        hsum[ci][v]=sb1[ci];
    }
    for (int idx=tid; idx<64*32; idx+=256){
        hsum[0][0]; // no-op
        int ci=idx>>5, p=idx&31;
        csum[ci][p]=sb2[ci];
    }
    __syncthreads();
    // stage 1: conv1 partials over ci slice, all 34 h positions (2 passes)
    #pragma unroll
    for (int pp=0;pp<2;pp++){
        const int v0=pp*17;
        float a[17];
        #pragma unroll
        for (int i=0;i<17;i++) a[i]=0.f;
        #pragma unroll 4
        for (int t=0;t<16;t++){
            const int ci=ci0+t;
            float x[19];
            #pragma unroll
            for (int j=0;j<19;j++) x[j]=ye[ci][v0+j];
            const float w0=wr[t*3+0], w1_=wr[t*3+1], w2_=wr[t*3+2];
            #pragma unroll
            for (int i=0;i<17;i++) a[i]+=w0*x[i]+w1_*x[i+1]+w2_*x[i+2];
        }
        #pragma unroll
        for (int i=0;i<17;i++) atomicAdd(&hsum[co][v0+i], a[i]);
    }
    // preload stage-2 weights (reuse wr)
    {
        const float* wbase = w2t + co;
        #pragma unroll
        for (int t=0;t<16;t++){
            const float* wp = wbase + (ci0+t)*192;
            wr[t*3+0]=wp[0]; wr[t*3+1]=wp[64]; wr[t*3+2]=wp[128];
        }
    }
    __syncthreads();
    // gelu pass (+ zero h outside [0,LSEQ) — reference zero-pads h itself)
    for (int idx=tid; idx<64*34; idx+=256){
        int ci=idx/34, v=idx-ci*34;
        int ph=l0-1+v;
        float hv=hsum[ci][v];
        hsum[ci][v] = (ph>=0 && ph<LSEQ)? geluf(hv) : 0.f;
    }
    __syncthreads();
    // stage 2: conv2 partials over ci slice, 32 out positions (2 passes)
    #pragma unroll
    for (int pp=0;pp<2;pp++){
        const int p0=pp*16;
        float a[16];
        #pragma unroll
        for (int i=0;i<16;i++) a[i]=0.f;
        #pragma unroll 4
        for (int t=0;t<16;t++){
            const int ci=ci0+t;
            float x[18];
            #pragma unroll
            for (int j=0;j<18;j++) x[j]=hsum[ci][p0+j];
            const float w0=wr[t*3+0], w1_=wr[t*3+1], w2_=wr[t*3+2];
            #pragma unroll
            for (int i=0;i<16;i++) a[i]+=w0*x[i]+w1_*x[i+1]+w2_*x[i+2];
        }
        #pragma unroll
        for (int i=0;i<16;i++) atomicAdd(&csum[co][p0+i], a[i]);
    }
    __syncthreads();
    // modulation + silu - leak (each thread owns 8 positions of its co)
    {
        const float sc=modscB[lvl*576+tslot*64+co];
        const float bi=modbiB[lvl*576+tslot*64+co];
        const int p0=w*8;
        #pragma unroll
        for (int i=0;i<8;i++){
            float m=csum[co][p0+i]*sc+bi;
            csum[co][p0+i]=siluf(m)-0.1f*ye[co][p0+i+2];
        }
    }
    __syncthreads();
    // epilogue: coalesced global updates
    float esum=0.f;
    const float dt6=dt/6.0f;
    for (int idx=tid; idx<64*TP; idx+=256){
        int ci=idx>>5, p=idx&(TP-1);
        float k=csum[ci][p];
        size_t gi=(size_t)(b*64+ci)*LSEQ + l0+p;
        if (eval==0){ kout[gi]=k; acc[gi]=k; }
        else if (eval<3){ kout[gi]=k; acc[gi]+=2.0f*k; }
        else {
            float yn=yin[gi]+dt6*(acc[gi]+k);
            yout[gi]=yn;
            esum+=yn*yn;
        }
    }
    if (do_energy){
        for (int o=32;o>0;o>>=1) esum+=__shfl_down(esum,o,64);
        if ((tid&63)==0) red[tid>>6]=esum;
        __syncthreads();
        if (tid==0) atomicAdd(&eoutB[lvl*8+b], red[0]+red[1]+red[2]+red[3]);
    }
}

// ---------------- energy renorm (batched over levels) -----------------------
__global__ __launch_bounds__(256) void scale_kernel(
    const float* __restrict__ y, const float* __restrict__ ein,
    const float* __restrict__ eout, float* __restrict__ o)
{
    int idx = blockIdx.x*256 + threadIdx.x;
    int lb = idx>>17;   // (lvl*8+b), 131072 elems each
    float eo = eout[lb]*(1.0f/131072.0f);
    o[idx] = y[idx]*sqrtf(ein[lb]/(eo+1e-8f));
}

// ---------------- 1x1 attention, detail *= (1+a) in place -------------------
__global__ __launch_bounds__(256) void attn_kernel(
    const float* __restrict__ cur, float* __restrict__ detail,
    const float* __restrict__ a1w, const float* __restrict__ a1b,
    const float* __restrict__ a2w, const float* __restrict__ a2b)
{
    __shared__ float c[64][64];
    __shared__ float hid[16][64];
    const int tid=threadIdx.x, b=blockIdx.y, l0=blockIdx.x*64;
    for (int idx=tid; idx<4096; idx+=256){
        int ci=idx>>6, p=idx&63;
        c[ci][p]=cur[(size_t)(b*64+ci)*LSEQ+l0+p];
    }
    __syncthreads();
    for (int idx=tid; idx<1024; idx+=256){
        int h=idx>>6, p=idx&63;
        float acc=a1b[h];
        const float* W=a1w+h*64;
        for (int ci=0;ci<64;ci++) acc += W[ci]*c[ci][p];
        hid[h][p]=geluf(acc);
    }
    __syncthreads();
    for (int idx=tid; idx<4096; idx+=256){
        int co=idx>>6, p=idx&63;
        float acc=a2b[co];
        const float* W=a2w+co*16;
        #pragma unroll
        for (int h=0;h<16;h++) acc += W[h]*hid[h][p];
        float a=sigf(acc);
        size_t gi=(size_t)(b*64+co)*LSEQ+l0+p;
        detail[gi] *= (1.0f+a);
    }
}

// ---------------- gate conv + residual update -------------------------------
__global__ __launch_bounds__(256) void gate_kernel(
    const float* __restrict__ cur, const float* __restrict__ detail,
    const float* __restrict__ gwt, const float* __restrict__ gb,
    float* __restrict__ curout)
{
    __shared__ float yc[64][66];
    __shared__ float dtile[64][65];
    const int tid=threadIdx.x, b=blockIdx.y, l0=blockIdx.x*64;
    for (int idx=tid; idx<64*66; idx+=256){
        int ci=idx/66, u=idx-ci*66;
        int l=l0+u-1;
        yc[ci][u]=(l>=0 && l<LSEQ)? cur[(size_t)(b*64+ci)*LSEQ+l] : 0.f;
    }
    for (int idx=tid; idx<4096; idx+=256){
        int ci=idx>>6, p=idx&63;
        dtile[ci][p]=detail[(size_t)(b*64+ci)*LSEQ+l0+p];
    }
    __syncthreads();
    const int co=tid&63, g=tid>>6;
    const int p0=g*16;
    float a[16];
    float bb=gb[co];
    #pragma unroll
    for (int i=0;i<16;i++) a[i]=bb;
    for (int ci=0;ci<64;ci++){
        float w0=gwt[(ci*3+0)*64+co];
        float w1_=gwt[(ci*3+1)*64+co];
        float w2_=gwt[(ci*3+2)*64+co];
        float x[18];
        #pragma unroll
        for (int j=0;j<18;j++) x[j]=yc[ci][p0+j];
        #pragma unroll
        for (int i=0;i<16;i++) a[i] += w0*x[i]+w1_*x[i+1]+w2_*x[i+2];
    }
    float r[16];
    #pragma unroll
    for (int i=0;i<16;i++){
        float gt=sigf(a[i]);
        r[i]=yc[co][p0+i+1]+gt*dtile[co][p0+i];
    }
    __syncthreads();
    #pragma unroll
    for (int i=0;i<16;i++) dtile[co][p0+i]=r[i];
    __syncthreads();
    for (int idx=tid; idx<4096; idx+=256){
        int ci=idx>>6, p=idx&63;
        curout[(size_t)(b*64+ci)*LSEQ+l0+p]=dtile[ci][p];
    }
}

extern "C" void kernel_launch(void* const* d_in, const int* in_sizes, int n_in,
                              void* d_out, int out_size, void* d_ws, size_t ws_size,
                              hipStream_t stream)
{
    (void)in_sizes; (void)n_in; (void)out_size; (void)ws_size;
    const float* x       =(const float*)d_in[0];
    const float* dy_w1   =(const float*)d_in[1];
    const float* dy_b1   =(const float*)d_in[2];
    const float* dy_wg1  =(const float*)d_in[3];
    const float* dy_bg1  =(const float*)d_in[4];
    const float* dy_wg2  =(const float*)d_in[5];
    const float* dy_bg2  =(const float*)d_in[6];
    const float* ode_c1w =(const float*)d_in[7];
    const float* ode_c1b =(const float*)d_in[8];
    const float* ode_c2w =(const float*)d_in[9];
    const float* ode_c2b =(const float*)d_in[10];
    const float* ode_wt  =(const float*)d_in[11];
    const float* ode_bt  =(const float*)d_in[12];
    const float* ode_wm  =(const float*)d_in[13];
    const float* ode_bm  =(const float*)d_in[14];
    const float* ode_emb =(const float*)d_in[15];
    const float* gate_w  =(const float*)d_in[16];
    const float* gate_b  =(const float*)d_in[17];
    const float* attn1_w =(const float*)d_in[18];
    const float* attn1_b =(const float*)d_in[19];
    const float* attn2_w =(const float*)d_in[20];
    const float* attn2_b =(const float*)d_in[21];
    float* out=(float*)d_out;
    float* ws=(float*)d_ws;
    const size_t N=NTOT;
    // workspace layout (floats): 20N + ~190K ≈ 85 MB (ws is ~256 MB)
    float* CB = ws;          // coeff[4]: A0, D1, D2, D3 (4N)
    float* PB = ws+4*N;      // y ping (4 levels) — also decomp temps T0,T1
    float* QB = ws+8*N;      // y pong (4 levels)
    float* K0B= ws+12*N;
    float* K1B= ws+16*N;
    float* SM = ws+20*N;
    float* stat_ws =SM;          // 512
    float* lo_ws   =SM+512;      // 64
    float* hi_ws   =SM+576;      // 64
    float* rowstats=SM+1024;     // 4*512*8 = 16384
    float* ts_ws   =SM+17408;    // 4*8
    float* modsc   =SM+17536;    // 4*576
    float* modbi   =SM+19840;    // 4*576
    float* ein     =SM+22144;    // 32
    float* eoutb   =SM+22176;    // 32
    float* WT      =SM+24576;    // 8*12288 (ode conv weights, transposed)
    float* WTG     =WT+8*12288;  // 3*12288 (gate weights, transposed)
    float* ACCB    =out;         // d_out[0..4N) free until scale_kernel

    dim3 blk(256);

    for (int lvl=0;lvl<4;lvl++){
        wtrans_kernel<<<48,blk,0,stream>>>(ode_c1w+(size_t)lvl*12288, WT+(size_t)(2*lvl)*12288);
        wtrans_kernel<<<48,blk,0,stream>>>(ode_c2w+(size_t)lvl*12288, WT+(size_t)(2*lvl+1)*12288);
    }
    for (int i=0;i<3;i++)
        wtrans_kernel<<<48,blk,0,stream>>>(gate_w+(size_t)i*12288, WTG+(size_t)i*12288);

    // ---- wavelet decomposition (3 levels, sequential) ----
    const float* cura=x;
    float* outsA[3]={PB, PB+N, CB};      // T0, T1, A0-final
    float* outsD[3]={CB+N, CB+2*N, CB+3*N};
    for (int lv=0; lv<3; lv++){
        stat_kernel<<<NROWS,blk,0,stream>>>(cura, stat_ws);
        dywan_kernel<<<1,blk,0,stream>>>(stat_ws, dy_w1,dy_b1,dy_wg1,dy_bg1,dy_wg2,dy_bg2,
                                         lo_ws, hi_ws, out+4*N);
        filt_kernel<<<dim3(8,NROWS),blk,0,stream>>>(cura, lo_ws, hi_ws, outsA[lv], outsD[lv]);
        cura=outsA[lv];
    }

    // ---- adaptive grids + modulation for all 4 levels ----
    tg_pass1<<<dim3(NROWS,4),blk,0,stream>>>(CB, rowstats);
    tg_finalize<<<4,blk,0,stream>>>(rowstats, ode_wt, ode_bt, ode_wm, ode_bm,
                                    ode_emb, ts_ws, modsc, modbi, ein, eoutb);

    // ---- RK4: 16 evals, each batched over 4 levels ----
    const float* yins[4]={CB, PB, QB, PB};
    float*       youts[4]={PB, QB, PB, QB};
    for (int step=0;step<4;step++){
        for (int ev=0;ev<4;ev++){
            const float* kp=(ev==0)?K0B:((ev==1)?K0B:((ev==2)?K1B:K0B));
            float* ko=(ev==0)?K0B:((ev==1)?K1B:((ev==2)?K0B:K0B));
            int doe=(step==3 && ev==3)?1:0;
            ode_eval_all<<<dim3(LSEQ/TP,NB,4),blk,0,stream>>>(
                yins[step],kp,ko,ACCB,youts[step],
                WT,ode_c1b,ode_c2b,modsc,modbi,ts_ws,eoutb,step,ev,doe);
        }
    }
    scale_kernel<<<4*NTOT/256,blk,0,stream>>>(QB, ein, eoutb, out);

    // ---- reconstruction ----
    // i=2: current: out0 -> PB; detail = out slot 3 (unchanged)
    gate_kernel<<<dim3(32,NB),blk,0,stream>>>(out+0*N, out+3*N, WTG+2*12288, gate_b+2*64, PB);
    // i=1: attn modifies out slot 2 in place, then gate: PB -> QB
    attn_kernel<<<dim3(32,NB),blk,0,stream>>>(PB, out+2*N, attn1_w+1024, attn1_b+16,
                                              attn2_w+1024, attn2_b+64);
    gate_kernel<<<dim3(32,NB),blk,0,stream>>>(PB, out+2*N, WTG+1*12288, gate_b+64, QB);
    // i=0: attn modifies out slot 1 in place, then gate: QB -> out slot 0
    attn_kernel<<<dim3(32,NB),blk,0,stream>>>(QB, out+1*N, attn1_w, attn1_b,
                                              attn2_w, attn2_b);
    gate_kernel<<<dim3(32,NB),blk,0,stream>>>(QB, out+1*N, WTG, gate_b, out+0*N);
}

// Round 6
// 2640.353 us; speedup vs baseline: 1.6771x; 1.6771x over previous
//
#include <hip/hip_runtime.h>
#include <math.h>

#define LSEQ 2048
#define NB 8
#define NCH 64
#define NTOT (NB*NCH*LSEQ)   // 1048576
#define NROWS (NB*NCH)       // 512
#define TP 62                // ode eval tile: 62 outputs, 64 h-positions = 1 wave

__device__ __forceinline__ float geluf(float x){
    return 0.5f*x*(1.0f+erff(x*0.70710678118654752f));
}
__device__ __forceinline__ float siluf(float x){
    return x/(1.0f+expf(-x));
}
__device__ __forceinline__ float sigf(float x){
    return 1.0f/(1.0f+expf(-x));
}

// ---------------- weight transpose: w[64][64][3] -> wt[192][64] (gate) ------
__global__ __launch_bounds__(256) void wtrans_kernel(const float* __restrict__ w,
                                                     float* __restrict__ wt){
    int idx = blockIdx.x*256 + threadIdx.x;   // 12288 total
    int j = idx >> 6, co = idx & 63;
    wt[idx] = w[co*192 + j];
}

// ---- ode weight prep: WS[lvl][st][g][ci][48], k=(co%16)*3+tap --------------
__global__ __launch_bounds__(256) void wprep_kernel(const float* __restrict__ c1w,
                                                    const float* __restrict__ c2w,
                                                    float* __restrict__ WS){
    int idx = blockIdx.x*256 + threadIdx.x;   // 98304 total
    int k  = idx % 48;
    int ci = (idx/48) & 63;
    int g  = (idx/(48*64)) & 3;
    int st = (idx/(48*64*4)) & 1;
    int lvl= idx/(48*64*8);
    int co = g*16 + k/3;
    int tap= k - (k/3)*3;
    const float* src = (st==0? c1w : c2w);
    WS[idx] = src[(size_t)lvl*12288 + co*192 + ci*3 + tap];
}

// ---------------- stat = mean over L ----------------------------------------
__global__ __launch_bounds__(256) void stat_kernel(const float* __restrict__ in,
                                                   float* __restrict__ stat){
    int r = blockIdx.x, tid = threadIdx.x;
    const float* p = in + (size_t)r*LSEQ;
    float acc = 0.f;
    for (int i=tid;i<LSEQ;i+=256) acc += p[i];
    for (int o=32;o>0;o>>=1) acc += __shfl_down(acc,o,64);
    __shared__ float red[4];
    if ((tid&63)==0) red[tid>>6]=acc;
    __syncthreads();
    if (tid==0) stat[r] = (red[0]+red[1]+red[2]+red[3])*(1.0f/LSEQ);
}

// ---------------- dywan MLP + filters + ortho -------------------------------
__global__ __launch_bounds__(256) void dywan_kernel(
    const float* __restrict__ stat,
    const float* __restrict__ w1, const float* __restrict__ b1,
    const float* __restrict__ wg1, const float* __restrict__ bg1,
    const float* __restrict__ wg2, const float* __restrict__ bg2,
    float* __restrict__ lo_out, float* __restrict__ hi_out,
    float* __restrict__ ortho_out)
{
    __shared__ float st[512];
    __shared__ float h1s[512];
    __shared__ float h2s[1024];
    __shared__ float fs[112];
    int tid = threadIdx.x;
    for (int i=tid;i<512;i+=256) st[i]=stat[i];
    __syncthreads();
    for (int idx=tid; idx<512; idx+=256){
        int b=idx>>6, j=idx&63;
        float acc=b1[j];
        const float* W=w1+j*64;
        for (int i=0;i<64;i++) acc += st[b*64+i]*W[i];
        h1s[idx]=geluf(acc);
    }
    __syncthreads();
    for (int idx=tid; idx<1024; idx+=256){
        int b=idx>>7, j=idx&127;
        float acc=bg1[j];
        const float* W=wg1+j*64;
        for (int i=0;i<64;i++) acc += h1s[b*64+i]*W[i];
        h2s[idx]=geluf(acc);
    }
    __syncthreads();
    if (tid<112){
        int b=tid/14, j=tid-b*14;
        float acc=bg2[j];
        const float* W=wg2+j*128;
        for (int i=0;i<128;i++) acc += h2s[b*128+i]*W[i];
        fs[tid]=acc;
    }
    __syncthreads();
    if (tid<56){
        int b=tid/7, k=tid-b*7;
        lo_out[tid]=fs[b*14+k];
        hi_out[tid]=fs[b*14+7+k];
    }
    if (tid==0){
        float smooth=0.f, shiftsum=0.f, ampsum=0.f;
        for (int b=0;b<8;b++){
            const float* l = fs + b*14;   // lo row
            float prev=0.f, nrm=0.f;
            for (int k=0;k<7;k++){ smooth += fabsf(l[k]-prev); prev=l[k]; nrm += l[k]*l[k]; }
            smooth += fabsf(prev);
            float denom = sqrtf(nrm) + 1e-8f;
            float sabs=0.f, s2=0.f;
            for (int k=0;k<7;k++){ float v=l[k]/denom; sabs+=fabsf(v); s2+=v*v; }
            shiftsum += sabs*sabs;
            ampsum += fabsf(s2-1.0f);
        }
        smooth *= (1.0f/64.0f);
        float shift = 3.0f*shiftsum/(8.0f*49.0f);
        float amp = ampsum*(1.0f/8.0f);
        *ortho_out = 0.01f*(shift+amp) + 0.1f*smooth;
    }
}

// ---------------- per-batch 7-tap filter conv (edge pad) --------------------
__global__ __launch_bounds__(256) void filt_kernel(
    const float* __restrict__ ap, const float* __restrict__ lo,
    const float* __restrict__ hi, float* __restrict__ na,
    float* __restrict__ det)
{
    int r = blockIdx.y, l0 = blockIdx.x*256, tid = threadIdx.x;
    int b = r>>6;
    __shared__ float s[262];
    __shared__ float fl[7], fh[7];
    for (int idx=tid; idx<262; idx+=256){
        int l = l0+idx-3;
        l = min(max(l,0),LSEQ-1);
        s[idx]=ap[(size_t)r*LSEQ+l];
    }
    if (tid<7) fl[tid]=lo[b*7+tid];
    else if (tid<14) fh[tid-7]=hi[b*7+tid-7];
    __syncthreads();
    float a=0.f, d=0.f;
    #pragma unroll
    for (int k=0;k<7;k++){ float v=s[tid+k]; a+=v*fl[k]; d+=v*fh[k]; }
    na[(size_t)r*LSEQ+l0+tid]=a;
    det[(size_t)r*LSEQ+l0+tid]=d;
}

// ---------------- time grid pass1: per-row stats (batched over levels) ------
__global__ __launch_bounds__(256) void tg_pass1(const float* __restrict__ CB,
                                                float* __restrict__ rowstats){
    __shared__ float sh[2048];
    __shared__ float red[28];
    int r = blockIdx.x, lvl = blockIdx.y, tid = threadIdx.x;
    const float* s = CB + (size_t)lvl*NTOT + (size_t)r*LSEQ;
    float* rso = rowstats + (size_t)(lvl*NROWS+r)*8;
    for (int i=tid;i<2048;i+=256) sh[i]=s[i];
    __syncthreads();
    float ssq=0.f;
    for (int i=tid;i<2048;i+=256){ float v=sh[i]; ssq+=v*v; }
    float mn=1e30f, mx=-1e30f, s0=0.f,s1=0.f,s2=0.f,s3=0.f;
    for (int j=tid;j<2047;j+=256){
        int k0 = (j-2>0)? j-2:0;
        int k1 = (j+2<2046)? j+2:2046;
        float acc=0.f;
        for (int k=k0;k<=k1;k++) acc += fabsf(sh[k+1]-sh[k]);
        float inten = acc*0.2f;
        mn=fminf(mn,inten); mx=fmaxf(mx,inten);
        if (j<511)  s0+=inten;
        if (j<1023) s1+=inten;
        if (j<1534) s2+=inten;
        if (j<2046) s3+=inten;
    }
    float vals[7]={mn,mx,s0,s1,s2,s3,ssq};
    for (int o=32;o>0;o>>=1){
        vals[0]=fminf(vals[0],__shfl_down(vals[0],o,64));
        vals[1]=fmaxf(vals[1],__shfl_down(vals[1],o,64));
        vals[2]+=__shfl_down(vals[2],o,64);
        vals[3]+=__shfl_down(vals[3],o,64);
        vals[4]+=__shfl_down(vals[4],o,64);
        vals[5]+=__shfl_down(vals[5],o,64);
        vals[6]+=__shfl_down(vals[6],o,64);
    }
    int lane=tid&63, w=tid>>6;
    if (lane==0) for (int q=0;q<7;q++) red[w*7+q]=vals[q];
    __syncthreads();
    if (tid==0){
        rso[0]=fminf(fminf(red[0],red[7]),fminf(red[14],red[21]));
        rso[1]=fmaxf(fmaxf(red[1],red[8]),fmaxf(red[15],red[22]));
        rso[2]=red[2]+red[9]+red[16]+red[23];
        rso[3]=red[3]+red[10]+red[17]+red[24];
        rso[4]=red[4]+red[11]+red[18]+red[25];
        rso[5]=red[5]+red[12]+red[19]+red[26];
        rso[6]=red[6]+red[13]+red[20]+red[27];
    }
}

// ---------------- time grid finalize + modulation (grid = 4 levels) ---------
__global__ __launch_bounds__(256) void tg_finalize(
    const float* __restrict__ rowstats,
    const float* __restrict__ wt, const float* __restrict__ bt,
    const float* __restrict__ wm, const float* __restrict__ bm,
    const float* __restrict__ emb,
    float* __restrict__ ts_out, float* __restrict__ modsc,
    float* __restrict__ modbi, float* __restrict__ ein,
    float* __restrict__ eout)
{
    int tid=threadIdx.x;
    const int lvl=blockIdx.x;
    const float* rs = rowstats + (size_t)lvl*NROWS*8;
    __shared__ float red[28];
    __shared__ float stv[9];
    __shared__ float temb[144];
    float mn=1e30f,mx=-1e30f,a0=0.f,a1=0.f,a2=0.f,a3=0.f,m3=-1e30f;
    for (int r=tid;r<512;r+=256){
        mn=fminf(mn,rs[r*8+0]); mx=fmaxf(mx,rs[r*8+1]);
        a0+=rs[r*8+2]; a1+=rs[r*8+3]; a2+=rs[r*8+4]; a3+=rs[r*8+5];
        m3=fmaxf(m3,rs[r*8+5]);
    }
    float vals[7]={mn,mx,a0,a1,a2,a3,m3};
    for (int o=32;o>0;o>>=1){
        vals[0]=fminf(vals[0],__shfl_down(vals[0],o,64));
        vals[1]=fmaxf(vals[1],__shfl_down(vals[1],o,64));
        vals[2]+=__shfl_down(vals[2],o,64);
        vals[3]+=__shfl_down(vals[3],o,64);
        vals[4]+=__shfl_down(vals[4],o,64);
        vals[5]+=__shfl_down(vals[5],o,64);
        vals[6]=fmaxf(vals[6],__shfl_down(vals[6],o,64));
    }
    int lane=tid&63, w=tid>>6;
    if (lane==0) for (int q=0;q<7;q++) red[w*7+q]=vals[q];
    if (tid<8){
        float e=0.f;
        for (int c=0;c<64;c++) e += rs[(tid*64+c)*8+6];
        ein[lvl*8+tid]=e*(1.0f/131072.0f);
        eout[lvl*8+tid]=0.f;
    }
    __syncthreads();
    if (tid==0){
        float mnv=fminf(fminf(red[0],red[7]),fminf(red[14],red[21]));
        float mxv=fmaxf(fmaxf(red[1],red[8]),fmaxf(red[15],red[22]));
        float s0=red[2]+red[9]+red[16]+red[23];
        float s1=red[3]+red[10]+red[17]+red[24];
        float s2=red[4]+red[11]+red[18]+red[25];
        float s3=red[5]+red[12]+red[19]+red[26];
        float m3v=fmaxf(fmaxf(red[6],red[13]),fmaxf(red[20],red[27]));
        const float idxs[5]={0.f,511.f,1023.f,1534.f,2046.f};
        float tsv[5];
        if (mxv-mnv < 1e-8f){
            for (int k=0;k<5;k++) tsv[k]=idxs[k]/2046.0f;
        } else {
            float a = 0.9f/(mxv-mnv+1e-30f);
            float bb = 0.1f - a*mnv;
            float gmax = a*m3v + bb*2046.0f;
            float sums[5]={0.f,s0,s1,s2,s3};
            tsv[0]=0.f;
            for (int k=1;k<5;k++)
                tsv[k]=(a*(sums[k]*(1.0f/512.0f)) + bb*idxs[k])/gmax;
        }
        for (int k=0;k<5;k++){ ts_out[lvl*8+k]=tsv[k]; stv[2*k]=tsv[k]; }
        for (int k=0;k<4;k++) stv[2*k+1]=tsv[k] + 0.5f*(tsv[k+1]-tsv[k]);
    }
    __syncthreads();
    if (tid<144){
        int m=tid>>4, i=tid&15;
        float z = wt[lvl*16+i]*stv[m] + bt[lvl*16+i];
        temb[tid]=siluf(z);
    }
    __syncthreads();
    for (int idx=tid; idx<1152; idx+=256){
        int m=idx>>7, c=idx&127;
        float g=bm[lvl*128+c];
        const float* W=wm+(size_t)(lvl*128+c)*16;
        const float* te=temb+m*16;
        for (int i=0;i<16;i++) g += W[i]*te[i];
        if (c<64) modsc[lvl*576+m*64+c]=1.0f+g+emb[(lvl*8+lvl)*64+c];
        else      modbi[lvl*576+m*64+(c-64)]=g;
    }
}

// ---------------- fused ode_f eval: lane = position, wave = 16-co slice -----
// grid (34, 8, 4): (pos tile of 62, batch, level). block 256 = 4 waves.
// Weights are wave-uniform (readfirstlane'd wave id) -> scalar-pipe loads.
// Per ci iter: 3 stride-1 ds_read + 12 uniform float4 weight loads + 48 FMA.
__global__ __launch_bounds__(256,4) void ode_eval_all(
    const float* __restrict__ yinB, const float* __restrict__ kprevB,
    float* __restrict__ koutB, float* __restrict__ accB,
    float* __restrict__ youtB,
    const float* __restrict__ WS, const float* __restrict__ c1bB,
    const float* __restrict__ c2bB,
    const float* __restrict__ modscB, const float* __restrict__ modbiB,
    const float* __restrict__ tsB, float* __restrict__ eoutB,
    int step, int eval, int do_energy)
{
    __shared__ float ye[64][68];   // u in [0,66): l = l0-2+u
    __shared__ float hs[64][66];   // v in [0,64): h pos = l0-1+v
    __shared__ float red[4];
    const int tid=threadIdx.x;
    const int lvl=blockIdx.z;
    const int b=blockIdx.y;
    const int l0=blockIdx.x*TP;
    const size_t loff=(size_t)lvl*NTOT;
    const float* yin = yinB + loff;
    const float* kprev = kprevB + loff;
    float* kout = koutB + loff;
    float* acc = accB + loff;
    float* yout = youtB + loff;
    const float dt = tsB[lvl*8+step+1]-tsB[lvl*8+step];
    const float alpha=(eval==0)?0.f:((eval==3)?dt:0.5f*dt);
    const int tslot=2*step+((eval==0)?0:((eval==3)?2:1));
    const int wv = __builtin_amdgcn_readfirstlane(tid>>6);
    const int lane = tid&63;
    const int co0 = wv*16;

    // stage 0: fill ye = yin + alpha*kprev (halo 2, zero-pad at seq ends)
    for (int idx=tid; idx<64*66; idx+=256){
        int ci=idx/66, u=idx-ci*66;
        int l=l0+u-2;
        float v=0.f;
        if (l>=0 && l<LSEQ){
            size_t gi=(size_t)(b*64+ci)*LSEQ+l;
            v=yin[gi];
            if (eval!=0) v+=alpha*kprev[gi];
        }
        ye[ci][u]=v;
    }
    __syncthreads();

    // stage 1: conv1 over all ci; lane computes h at pos l0-1+lane
    float a1[16];
    {
        const float* bb = c1bB + lvl*64 + co0;
        #pragma unroll
        for (int k=0;k<16;k++) a1[k]=bb[k];
    }
    {
        const float4* wq = (const float4*)(WS + (size_t)((lvl*2+0)*4 + wv)*3072);
        #pragma unroll 2
        for (int ci=0;ci<64;ci++){
            float x0=ye[ci][lane], x1=ye[ci][lane+1], x2=ye[ci][lane+2];
            const float4* wp = wq + ci*12;
            #pragma unroll
            for (int j=0;j<4;j++){
                float4 wa=wp[3*j], wb=wp[3*j+1], wc=wp[3*j+2];
                a1[4*j+0] += wa.x*x0 + wa.y*x1 + wa.z*x2;
                a1[4*j+1] += wa.w*x0 + wb.x*x1 + wb.y*x2;
                a1[4*j+2] += wb.z*x0 + wb.w*x1 + wc.x*x2;
                a1[4*j+3] += wc.y*x0 + wc.z*x1 + wc.w*x2;
            }
        }
    }
    {
        int ph = l0-1+lane;
        bool okh = (ph>=0 && ph<LSEQ);
        #pragma unroll
        for (int k=0;k<16;k++) hs[co0+k][lane] = okh ? geluf(a1[k]) : 0.f;
    }
    __syncthreads();

    // stage 2: conv2 over all ci; lane computes output at pos l0+lane
    float a2[16];
    {
        const float* bb = c2bB + lvl*64 + co0;
        #pragma unroll
        for (int k=0;k<16;k++) a2[k]=bb[k];
    }
    {
        const float4* wq = (const float4*)(WS + (size_t)((lvl*2+1)*4 + wv)*3072);
        #pragma unroll 2
        for (int ci=0;ci<64;ci++){
            float x0=hs[ci][lane], x1=hs[ci][lane+1], x2=hs[ci][lane+2];
            const float4* wp = wq + ci*12;
            #pragma unroll
            for (int j=0;j<4;j++){
                float4 wa=wp[3*j], wb=wp[3*j+1], wc=wp[3*j+2];
                a2[4*j+0] += wa.x*x0 + wa.y*x1 + wa.z*x2;
                a2[4*j+1] += wa.w*x0 + wb.x*x1 + wb.y*x2;
                a2[4*j+2] += wb.z*x0 + wb.w*x1 + wc.x*x2;
                a2[4*j+3] += wc.y*x0 + wc.z*x1 + wc.w*x2;
            }
        }
    }

    // modulation + silu - leak + global epilogue
    float esum=0.f;
    const float dt6=dt/6.0f;
    const bool okp = (lane<TP) && (l0+lane<LSEQ);
    const float* msc = modscB + lvl*576+tslot*64+co0;
    const float* mbi = modbiB + lvl*576+tslot*64+co0;
    #pragma unroll
    for (int k=0;k<16;k++){
        float m = a2[k]*msc[k] + mbi[k];
        float kv = siluf(m) - 0.1f*ye[co0+k][lane+2];
        if (okp){
            size_t gi=(size_t)(b*64+co0+k)*LSEQ + l0+lane;
            if (eval==0){ kout[gi]=kv; acc[gi]=kv; }
            else if (eval<3){ kout[gi]=kv; acc[gi]+=2.0f*kv; }
            else {
                float yn=yin[gi]+dt6*(acc[gi]+kv);
                yout[gi]=yn;
                esum+=yn*yn;
            }
        }
    }
    if (do_energy){
        for (int o=32;o>0;o>>=1) esum+=__shfl_down(esum,o,64);
        if ((tid&63)==0) red[tid>>6]=esum;
        __syncthreads();
        if (tid==0) atomicAdd(&eoutB[lvl*8+b], red[0]+red[1]+red[2]+red[3]);
    }
}

// ---------------- energy renorm (batched over levels) -----------------------
__global__ __launch_bounds__(256) void scale_kernel(
    const float* __restrict__ y, const float* __restrict__ ein,
    const float* __restrict__ eout, float* __restrict__ o)
{
    int idx = blockIdx.x*256 + threadIdx.x;
    int lb = idx>>17;   // (lvl*8+b), 131072 elems each
    float eo = eout[lb]*(1.0f/131072.0f);
    o[idx] = y[idx]*sqrtf(ein[lb]/(eo+1e-8f));
}

// ---------------- 1x1 attention, detail *= (1+a) in place -------------------
__global__ __launch_bounds__(256) void attn_kernel(
    const float* __restrict__ cur, float* __restrict__ detail,
    const float* __restrict__ a1w, const float* __restrict__ a1b,
    const float* __restrict__ a2w, const float* __restrict__ a2b)
{
    __shared__ float c[64][64];
    __shared__ float hid[16][64];
    const int tid=threadIdx.x, b=blockIdx.y, l0=blockIdx.x*64;
    for (int idx=tid; idx<4096; idx+=256){
        int ci=idx>>6, p=idx&63;
        c[ci][p]=cur[(size_t)(b*64+ci)*LSEQ+l0+p];
    }
    __syncthreads();
    for (int idx=tid; idx<1024; idx+=256){
        int h=idx>>6, p=idx&63;
        float acc=a1b[h];
        const float* W=a1w+h*64;
        for (int ci=0;ci<64;ci++) acc += W[ci]*c[ci][p];
        hid[h][p]=geluf(acc);
    }
    __syncthreads();
    for (int idx=tid; idx<4096; idx+=256){
        int co=idx>>6, p=idx&63;
        float acc=a2b[co];
        const float* W=a2w+co*16;
        #pragma unroll
        for (int h=0;h<16;h++) acc += W[h]*hid[h][p];
        float a=sigf(acc);
        size_t gi=(size_t)(b*64+co)*LSEQ+l0+p;
        detail[gi] *= (1.0f+a);
    }
}

// ---------------- gate conv + residual update -------------------------------
__global__ __launch_bounds__(256) void gate_kernel(
    const float* __restrict__ cur, const float* __restrict__ detail,
    const float* __restrict__ gwt, const float* __restrict__ gb,
    float* __restrict__ curout)
{
    __shared__ float yc[64][66];
    __shared__ float dtile[64][65];
    const int tid=threadIdx.x, b=blockIdx.y, l0=blockIdx.x*64;
    for (int idx=tid; idx<64*66; idx+=256){
        int ci=idx/66, u=idx-ci*66;
        int l=l0+u-1;
        yc[ci][u]=(l>=0 && l<LSEQ)? cur[(size_t)(b*64+ci)*LSEQ+l] : 0.f;
    }
    for (int idx=tid; idx<4096; idx+=256){
        int ci=idx>>6, p=idx&63;
        dtile[ci][p]=detail[(size_t)(b*64+ci)*LSEQ+l0+p];
    }
    __syncthreads();
    const int co=tid&63, g=tid>>6;
    const int p0=g*16;
    float a[16];
    float bb=gb[co];
    #pragma unroll
    for (int i=0;i<16;i++) a[i]=bb;
    for (int ci=0;ci<64;ci++){
        float w0=gwt[(ci*3+0)*64+co];
        float w1_=gwt[(ci*3+1)*64+co];
        float w2_=gwt[(ci*3+2)*64+co];
        float x[18];
        #pragma unroll
        for (int j=0;j<18;j++) x[j]=yc[ci][p0+j];
        #pragma unroll
        for (int i=0;i<16;i++) a[i] += w0*x[i]+w1_*x[i+1]+w2_*x[i+2];
    }
    float r[16];
    #pragma unroll
    for (int i=0;i<16;i++){
        float gt=sigf(a[i]);
        r[i]=yc[co][p0+i+1]+gt*dtile[co][p0+i];
    }
    __syncthreads();
    #pragma unroll
    for (int i=0;i<16;i++) dtile[co][p0+i]=r[i];
    __syncthreads();
    for (int idx=tid; idx<4096; idx+=256){
        int ci=idx>>6, p=idx&63;
        curout[(size_t)(b*64+ci)*LSEQ+l0+p]=dtile[ci][p];
    }
}

extern "C" void kernel_launch(void* const* d_in, const int* in_sizes, int n_in,
                              void* d_out, int out_size, void* d_ws, size_t ws_size,
                              hipStream_t stream)
{
    (void)in_sizes; (void)n_in; (void)out_size; (void)ws_size;
    const float* x       =(const float*)d_in[0];
    const float* dy_w1   =(const float*)d_in[1];
    const float* dy_b1   =(const float*)d_in[2];
    const float* dy_wg1  =(const float*)d_in[3];
    const float* dy_bg1  =(const float*)d_in[4];
    const float* dy_wg2  =(const float*)d_in[5];
    const float* dy_bg2  =(const float*)d_in[6];
    const float* ode_c1w =(const float*)d_in[7];
    const float* ode_c1b =(const float*)d_in[8];
    const float* ode_c2w =(const float*)d_in[9];
    const float* ode_c2b =(const float*)d_in[10];
    const float* ode_wt  =(const float*)d_in[11];
    const float* ode_bt  =(const float*)d_in[12];
    const float* ode_wm  =(const float*)d_in[13];
    const float* ode_bm  =(const float*)d_in[14];
    const float* ode_emb =(const float*)d_in[15];
    const float* gate_w  =(const float*)d_in[16];
    const float* gate_b  =(const float*)d_in[17];
    const float* attn1_w =(const float*)d_in[18];
    const float* attn1_b =(const float*)d_in[19];
    const float* attn2_w =(const float*)d_in[20];
    const float* attn2_b =(const float*)d_in[21];
    float* out=(float*)d_out;
    float* ws=(float*)d_ws;
    const size_t N=NTOT;
    // workspace layout (floats): 20N + ~190K ≈ 85 MB
    float* CB = ws;          // coeff[4]: A0, D1, D2, D3 (4N)
    float* PB = ws+4*N;      // y ping (4 levels) — also decomp temps T0,T1
    float* QB = ws+8*N;      // y pong (4 levels)
    float* K0B= ws+12*N;
    float* K1B= ws+16*N;
    float* SM = ws+20*N;
    float* stat_ws =SM;          // 512
    float* lo_ws   =SM+512;      // 64
    float* hi_ws   =SM+576;      // 64
    float* rowstats=SM+1024;     // 4*512*8 = 16384
    float* ts_ws   =SM+17408;    // 4*8
    float* modsc   =SM+17536;    // 4*576
    float* modbi   =SM+19840;    // 4*576
    float* ein     =SM+22144;    // 32
    float* eoutb   =SM+22176;    // 32
    float* WS      =SM+24576;    // 98304: ode weights [lvl][st][g][ci][48]
    float* WTG     =WS+98304;    // 3*12288 (gate weights, transposed)
    float* ACCB    =out;         // d_out[0..4N) free until scale_kernel

    dim3 blk(256);

    wprep_kernel<<<384,blk,0,stream>>>(ode_c1w, ode_c2w, WS);
    for (int i=0;i<3;i++)
        wtrans_kernel<<<48,blk,0,stream>>>(gate_w+(size_t)i*12288, WTG+(size_t)i*12288);

    // ---- wavelet decomposition (3 levels, sequential) ----
    const float* cura=x;
    float* outsA[3]={PB, PB+N, CB};      // T0, T1, A0-final
    float* outsD[3]={CB+N, CB+2*N, CB+3*N};
    for (int lv=0; lv<3; lv++){
        stat_kernel<<<NROWS,blk,0,stream>>>(cura, stat_ws);
        dywan_kernel<<<1,blk,0,stream>>>(stat_ws, dy_w1,dy_b1,dy_wg1,dy_bg1,dy_wg2,dy_bg2,
                                         lo_ws, hi_ws, out+4*N);
        filt_kernel<<<dim3(8,NROWS),blk,0,stream>>>(cura, lo_ws, hi_ws, outsA[lv], outsD[lv]);
        cura=outsA[lv];
    }

    // ---- adaptive grids + modulation for all 4 levels ----
    tg_pass1<<<dim3(NROWS,4),blk,0,stream>>>(CB, rowstats);
    tg_finalize<<<4,blk,0,stream>>>(rowstats, ode_wt, ode_bt, ode_wm, ode_bm,
                                    ode_emb, ts_ws, modsc, modbi, ein, eoutb);

    // ---- RK4: 16 evals, each batched over 4 levels ----
    const int NTILE = (LSEQ + TP - 1)/TP;   // 34
    const float* yins[4]={CB, PB, QB, PB};
    float*       youts[4]={PB, QB, PB, QB};
    for (int step=0;step<4;step++){
        for (int ev=0;ev<4;ev++){
            const float* kp=(ev==0)?K0B:((ev==1)?K0B:((ev==2)?K1B:K0B));
            float* ko=(ev==0)?K0B:((ev==1)?K1B:((ev==2)?K0B:K0B));
            int doe=(step==3 && ev==3)?1:0;
            ode_eval_all<<<dim3(NTILE,NB,4),blk,0,stream>>>(
                yins[step],kp,ko,ACCB,youts[step],
                WS,ode_c1b,ode_c2b,modsc,modbi,ts_ws,eoutb,step,ev,doe);
        }
    }
    scale_kernel<<<4*NTOT/256,blk,0,stream>>>(QB, ein, eoutb, out);

    // ---- reconstruction ----
    // i=2: current: out0 -> PB; detail = out slot 3 (unchanged)
    gate_kernel<<<dim3(32,NB),blk,0,stream>>>(out+0*N, out+3*N, WTG+2*12288, gate_b+2*64, PB);
    // i=1: attn modifies out slot 2 in place, then gate: PB -> QB
    attn_kernel<<<dim3(32,NB),blk,0,stream>>>(PB, out+2*N, attn1_w+1024, attn1_b+16,
                                              attn2_w+1024, attn2_b+64);
    gate_kernel<<<dim3(32,NB),blk,0,stream>>>(PB, out+2*N, WTG+1*12288, gate_b+64, QB);
    // i=0: attn modifies out slot 1 in place, then gate: QB -> out slot 0
    attn_kernel<<<dim3(32,NB),blk,0,stream>>>(QB, out+1*N, attn1_w, attn1_b,
                                              attn2_w, attn2_b);
    gate_kernel<<<dim3(32,NB),blk,0,stream>>>(QB, out+1*N, WTG, gate_b, out+0*N);
}

// Round 7
// 1582.048 us; speedup vs baseline: 2.7989x; 1.6689x over previous
//
#include <hip/hip_runtime.h>
#include <math.h>

#define LSEQ 2048
#define NB 8
#define NCH 64
#define NTOT (NB*NCH*LSEQ)   // 1048576
#define NROWS (NB*NCH)       // 512

__device__ __forceinline__ float geluf(float x){
    return 0.5f*x*(1.0f+erff(x*0.70710678118654752f));
}
__device__ __forceinline__ float siluf(float x){
    return x/(1.0f+expf(-x));
}
__device__ __forceinline__ float sigf(float x){
    return 1.0f/(1.0f+expf(-x));
}

// ---------------- weight transpose: w[64][64][3] -> wt[192][64] --------------
__global__ __launch_bounds__(256) void wtrans_kernel(const float* __restrict__ w,
                                                     float* __restrict__ wt){
    int idx = blockIdx.x*256 + threadIdx.x;   // 12288 total
    int j = idx >> 6, co = idx & 63;
    wt[idx] = w[co*192 + j];
}

// ---------------- stat = mean over L ----------------------------------------
__global__ __launch_bounds__(256) void stat_kernel(const float* __restrict__ in,
                                                   float* __restrict__ stat){
    int r = blockIdx.x, tid = threadIdx.x;
    const float* p = in + (size_t)r*LSEQ;
    float acc = 0.f;
    for (int i=tid;i<LSEQ;i+=256) acc += p[i];
    for (int o=32;o>0;o>>=1) acc += __shfl_down(acc,o,64);
    __shared__ float red[4];
    if ((tid&63)==0) red[tid>>6]=acc;
    __syncthreads();
    if (tid==0) stat[r] = (red[0]+red[1]+red[2]+red[3])*(1.0f/LSEQ);
}

// ---------------- dywan MLP + filters + ortho -------------------------------
__global__ __launch_bounds__(256) void dywan_kernel(
    const float* __restrict__ stat,
    const float* __restrict__ w1, const float* __restrict__ b1,
    const float* __restrict__ wg1, const float* __restrict__ bg1,
    const float* __restrict__ wg2, const float* __restrict__ bg2,
    float* __restrict__ lo_out, float* __restrict__ hi_out,
    float* __restrict__ ortho_out)
{
    __shared__ float st[512];
    __shared__ float h1s[512];
    __shared__ float h2s[1024];
    __shared__ float fs[112];
    int tid = threadIdx.x;
    for (int i=tid;i<512;i+=256) st[i]=stat[i];
    __syncthreads();
    for (int idx=tid; idx<512; idx+=256){
        int b=idx>>6, j=idx&63;
        float acc=b1[j];
        const float* W=w1+j*64;
        for (int i=0;i<64;i++) acc += st[b*64+i]*W[i];
        h1s[idx]=geluf(acc);
    }
    __syncthreads();
    for (int idx=tid; idx<1024; idx+=256){
        int b=idx>>7, j=idx&127;
        float acc=bg1[j];
        const float* W=wg1+j*64;
        for (int i=0;i<64;i++) acc += h1s[b*64+i]*W[i];
        h2s[idx]=geluf(acc);
    }
    __syncthreads();
    if (tid<112){
        int b=tid/14, j=tid-b*14;
        float acc=bg2[j];
        const float* W=wg2+j*128;
        for (int i=0;i<128;i++) acc += h2s[b*128+i]*W[i];
        fs[tid]=acc;
    }
    __syncthreads();
    if (tid<56){
        int b=tid/7, k=tid-b*7;
        lo_out[tid]=fs[b*14+k];
        hi_out[tid]=fs[b*14+7+k];
    }
    if (tid==0){
        float smooth=0.f, shiftsum=0.f, ampsum=0.f;
        for (int b=0;b<8;b++){
            const float* l = fs + b*14;   // lo row
            float prev=0.f, nrm=0.f;
            for (int k=0;k<7;k++){ smooth += fabsf(l[k]-prev); prev=l[k]; nrm += l[k]*l[k]; }
            smooth += fabsf(prev);
            float denom = sqrtf(nrm) + 1e-8f;
            float sabs=0.f, s2=0.f;
            for (int k=0;k<7;k++){ float v=l[k]/denom; sabs+=fabsf(v); s2+=v*v; }
            shiftsum += sabs*sabs;
            ampsum += fabsf(s2-1.0f);
        }
        smooth *= (1.0f/64.0f);
        float shift = 3.0f*shiftsum/(8.0f*49.0f);
        float amp = ampsum*(1.0f/8.0f);
        *ortho_out = 0.01f*(shift+amp) + 0.1f*smooth;
    }
}

// ---------------- per-batch 7-tap filter conv (edge pad) --------------------
__global__ __launch_bounds__(256) void filt_kernel(
    const float* __restrict__ ap, const float* __restrict__ lo,
    const float* __restrict__ hi, float* __restrict__ na,
    float* __restrict__ det)
{
    int r = blockIdx.y, l0 = blockIdx.x*256, tid = threadIdx.x;
    int b = r>>6;
    __shared__ float s[262];
    __shared__ float fl[7], fh[7];
    for (int idx=tid; idx<262; idx+=256){
        int l = l0+idx-3;
        l = min(max(l,0),LSEQ-1);
        s[idx]=ap[(size_t)r*LSEQ+l];
    }
    if (tid<7) fl[tid]=lo[b*7+tid];
    else if (tid<14) fh[tid-7]=hi[b*7+tid-7];
    __syncthreads();
    float a=0.f, d=0.f;
    #pragma unroll
    for (int k=0;k<7;k++){ float v=s[tid+k]; a+=v*fl[k]; d+=v*fh[k]; }
    na[(size_t)r*LSEQ+l0+tid]=a;
    det[(size_t)r*LSEQ+l0+tid]=d;
}

// ---------------- time grid pass1: per-row stats (batched over levels) ------
__global__ __launch_bounds__(256) void tg_pass1(const float* __restrict__ CB,
                                                float* __restrict__ rowstats){
    __shared__ float sh[2048];
    __shared__ float red[28];
    int r = blockIdx.x, lvl = blockIdx.y, tid = threadIdx.x;
    const float* s = CB + (size_t)lvl*NTOT + (size_t)r*LSEQ;
    float* rso = rowstats + (size_t)(lvl*NROWS+r)*8;
    for (int i=tid;i<2048;i+=256) sh[i]=s[i];
    __syncthreads();
    float ssq=0.f;
    for (int i=tid;i<2048;i+=256){ float v=sh[i]; ssq+=v*v; }
    float mn=1e30f, mx=-1e30f, s0=0.f,s1=0.f,s2=0.f,s3=0.f;
    for (int j=tid;j<2047;j+=256){
        int k0 = (j-2>0)? j-2:0;
        int k1 = (j+2<2046)? j+2:2046;
        float acc=0.f;
        for (int k=k0;k<=k1;k++) acc += fabsf(sh[k+1]-sh[k]);
        float inten = acc*0.2f;
        mn=fminf(mn,inten); mx=fmaxf(mx,inten);
        if (j<511)  s0+=inten;
        if (j<1023) s1+=inten;
        if (j<1534) s2+=inten;
        if (j<2046) s3+=inten;
    }
    float vals[7]={mn,mx,s0,s1,s2,s3,ssq};
    for (int o=32;o>0;o>>=1){
        vals[0]=fminf(vals[0],__shfl_down(vals[0],o,64));
        vals[1]=fmaxf(vals[1],__shfl_down(vals[1],o,64));
        vals[2]+=__shfl_down(vals[2],o,64);
        vals[3]+=__shfl_down(vals[3],o,64);
        vals[4]+=__shfl_down(vals[4],o,64);
        vals[5]+=__shfl_down(vals[5],o,64);
        vals[6]+=__shfl_down(vals[6],o,64);
    }
    int lane=tid&63, w=tid>>6;
    if (lane==0) for (int q=0;q<7;q++) red[w*7+q]=vals[q];
    __syncthreads();
    if (tid==0){
        rso[0]=fminf(fminf(red[0],red[7]),fminf(red[14],red[21]));
        rso[1]=fmaxf(fmaxf(red[1],red[8]),fmaxf(red[15],red[22]));
        rso[2]=red[2]+red[9]+red[16]+red[23];
        rso[3]=red[3]+red[10]+red[17]+red[24];
        rso[4]=red[4]+red[11]+red[18]+red[25];
        rso[5]=red[5]+red[12]+red[19]+red[26];
        rso[6]=red[6]+red[13]+red[20]+red[27];
    }
}

// ---------------- time grid finalize + modulation (grid = 4 levels) ---------
__global__ __launch_bounds__(256) void tg_finalize(
    const float* __restrict__ rowstats,
    const float* __restrict__ wt, const float* __restrict__ bt,
    const float* __restrict__ wm, const float* __restrict__ bm,
    const float* __restrict__ emb,
    float* __restrict__ ts_out, float* __restrict__ modsc,
    float* __restrict__ modbi, float* __restrict__ ein,
    float* __restrict__ eout)
{
    int tid=threadIdx.x;
    const int lvl=blockIdx.x;
    const float* rs = rowstats + (size_t)lvl*NROWS*8;
    __shared__ float red[28];
    __shared__ float stv[9];
    __shared__ float temb[144];
    float mn=1e30f,mx=-1e30f,a0=0.f,a1=0.f,a2=0.f,a3=0.f,m3=-1e30f;
    for (int r=tid;r<512;r+=256){
        mn=fminf(mn,rs[r*8+0]); mx=fmaxf(mx,rs[r*8+1]);
        a0+=rs[r*8+2]; a1+=rs[r*8+3]; a2+=rs[r*8+4]; a3+=rs[r*8+5];
        m3=fmaxf(m3,rs[r*8+5]);
    }
    float vals[7]={mn,mx,a0,a1,a2,a3,m3};
    for (int o=32;o>0;o>>=1){
        vals[0]=fminf(vals[0],__shfl_down(vals[0],o,64));
        vals[1]=fmaxf(vals[1],__shfl_down(vals[1],o,64));
        vals[2]+=__shfl_down(vals[2],o,64);
        vals[3]+=__shfl_down(vals[3],o,64);
        vals[4]+=__shfl_down(vals[4],o,64);
        vals[5]+=__shfl_down(vals[5],o,64);
        vals[6]=fmaxf(vals[6],__shfl_down(vals[6],o,64));
    }
    int lane=tid&63, w=tid>>6;
    if (lane==0) for (int q=0;q<7;q++) red[w*7+q]=vals[q];
    if (tid<8){
        float e=0.f;
        for (int c=0;c<64;c++) e += rs[(tid*64+c)*8+6];
        ein[lvl*8+tid]=e*(1.0f/131072.0f);
        eout[lvl*8+tid]=0.f;
    }
    __syncthreads();
    if (tid==0){
        float mnv=fminf(fminf(red[0],red[7]),fminf(red[14],red[21]));
        float mxv=fmaxf(fmaxf(red[1],red[8]),fmaxf(red[15],red[22]));
        float s0=red[2]+red[9]+red[16]+red[23];
        float s1=red[3]+red[10]+red[17]+red[24];
        float s2=red[4]+red[11]+red[18]+red[25];
        float s3=red[5]+red[12]+red[19]+red[26];
        float m3v=fmaxf(fmaxf(red[6],red[13]),fmaxf(red[20],red[27]));
        const float idxs[5]={0.f,511.f,1023.f,1534.f,2046.f};
        float tsv[5];
        if (mxv-mnv < 1e-8f){
            for (int k=0;k<5;k++) tsv[k]=idxs[k]/2046.0f;
        } else {
            float a = 0.9f/(mxv-mnv+1e-30f);
            float bb = 0.1f - a*mnv;
            float gmax = a*m3v + bb*2046.0f;
            float sums[5]={0.f,s0,s1,s2,s3};
            tsv[0]=0.f;
            for (int k=1;k<5;k++)
                tsv[k]=(a*(sums[k]*(1.0f/512.0f)) + bb*idxs[k])/gmax;
        }
        for (int k=0;k<5;k++){ ts_out[lvl*8+k]=tsv[k]; stv[2*k]=tsv[k]; }
        for (int k=0;k<4;k++) stv[2*k+1]=tsv[k] + 0.5f*(tsv[k+1]-tsv[k]);
    }
    __syncthreads();
    if (tid<144){
        int m=tid>>4, i=tid&15;
        float z = wt[lvl*16+i]*stv[m] + bt[lvl*16+i];
        temb[tid]=siluf(z);
    }
    __syncthreads();
    for (int idx=tid; idx<1152; idx+=256){
        int m=idx>>7, c=idx&127;
        float g=bm[lvl*128+c];
        const float* W=wm+(size_t)(lvl*128+c)*16;
        const float* te=temb+m*16;
        for (int i=0;i<16;i++) g += W[i]*te[i];
        if (c<64) modsc[lvl*576+m*64+c]=1.0f+g+emb[(lvl*8+lvl)*64+c];
        else      modbi[lvl*576+m*64+(c-64)]=g;
    }
}

// ---------------- fused ode_f eval: lane = co, wave = 16-pos slice ----------
// grid (32, 8, 4): (64-pos tile, batch, level). block 256 = 4 waves.
// x-windows read as 5 wave-uniform ds_read_b128 per ci (aligned: stride 68).
// Weights: 3 coalesced dword loads per ci (lane-indexed, L1-resident).
// Stage 1: wave w computes h[16w .. 16w+18) (2-pos overlap writes identical
// values — benign). Stage 2: wave w computes out[16w .. 16w+16).
__global__ __launch_bounds__(256,4) void ode_eval_all(
    const float* __restrict__ yinB, const float* __restrict__ kprevB,
    float* __restrict__ koutB, float* __restrict__ accB,
    float* __restrict__ youtB,
    const float* __restrict__ wtB, const float* __restrict__ c1bB,
    const float* __restrict__ c2bB,
    const float* __restrict__ modscB, const float* __restrict__ modbiB,
    const float* __restrict__ tsB, float* __restrict__ eoutB,
    int step, int eval, int do_energy)
{
    __shared__ float ye[64][68];   // u in [0,68): l = l0-2+u
    __shared__ float hs[64][68];   // v in [0,66): h pos = l0-1+v
    __shared__ float red[4];
    const int tid=threadIdx.x;
    const int lvl=blockIdx.z;
    const int b=blockIdx.y;
    const int l0=blockIdx.x*64;
    const size_t loff=(size_t)lvl*NTOT;
    const float* yin = yinB + loff;
    const float* kprev = kprevB + loff;
    float* kout = koutB + loff;
    float* acc = accB + loff;
    float* yout = youtB + loff;
    const float* w1t = wtB + (size_t)lvl*24576;
    const float* w2t = w1t + 12288;
    const float dt = tsB[lvl*8+step+1]-tsB[lvl*8+step];
    const float alpha=(eval==0)?0.f:((eval==3)?dt:0.5f*dt);
    const int tslot=2*step+((eval==0)?0:((eval==3)?2:1));
    const int w=tid>>6, co=tid&63;
    const int v0=w*16;

    // stage 0: fill ye = yin + alpha*kprev (halo 2, zero-pad at seq ends)
    for (int idx=tid; idx<64*68; idx+=256){
        int ci=idx/68, u=idx-ci*68;
        int l=l0+u-2;
        float v=0.f;
        if (l>=0 && l<LSEQ){
            size_t gi=(size_t)(b*64+ci)*LSEQ+l;
            v=yin[gi];
            if (eval!=0) v+=alpha*kprev[gi];
        }
        ye[ci][u]=v;
    }
    __syncthreads();

    // stage 1: conv1 + gelu; wave computes h positions v in [v0, v0+18)
    {
        float a1[18];
        const float bb=c1bB[lvl*64+co];
        #pragma unroll
        for (int i=0;i<18;i++) a1[i]=bb;
        #pragma unroll 2
        for (int ci=0;ci<64;ci++){
            const float4* yq=(const float4*)&ye[ci][v0];
            float4 q0=yq[0], q1=yq[1], q2=yq[2], q3=yq[3], q4=yq[4];
            float x[20]={q0.x,q0.y,q0.z,q0.w, q1.x,q1.y,q1.z,q1.w,
                         q2.x,q2.y,q2.z,q2.w, q3.x,q3.y,q3.z,q3.w,
                         q4.x,q4.y,q4.z,q4.w};
            const float* wp=w1t+ci*192+co;
            float w0=wp[0], w1_=wp[64], w2_=wp[128];
            #pragma unroll
            for (int i=0;i<18;i++) a1[i]+=w0*x[i]+w1_*x[i+1]+w2_*x[i+2];
        }
        #pragma unroll
        for (int i=0;i<18;i++){
            int ph=l0-1+v0+i;
            hs[co][v0+i] = (ph>=0 && ph<LSEQ)? geluf(a1[i]) : 0.f;
        }
    }
    __syncthreads();

    // stage 2: conv2; wave computes out positions p in [v0, v0+16)
    float kv[16];
    {
        float a2[16];
        const float bb=c2bB[lvl*64+co];
        #pragma unroll
        for (int i=0;i<16;i++) a2[i]=bb;
        #pragma unroll 2
        for (int ci=0;ci<64;ci++){
            const float4* hq=(const float4*)&hs[ci][v0];
            float4 q0=hq[0], q1=hq[1], q2=hq[2], q3=hq[3], q4=hq[4];
            float x[18]={q0.x,q0.y,q0.z,q0.w, q1.x,q1.y,q1.z,q1.w,
                         q2.x,q2.y,q2.z,q2.w, q3.x,q3.y,q3.z,q3.w,
                         q4.x,q4.y};
            const float* wp=w2t+ci*192+co;
            float w0=wp[0], w1_=wp[64], w2_=wp[128];
            #pragma unroll
            for (int i=0;i<16;i++) a2[i]+=w0*x[i]+w1_*x[i+1]+w2_*x[i+2];
        }
        const float sc=modscB[lvl*576+tslot*64+co];
        const float bi=modbiB[lvl*576+tslot*64+co];
        #pragma unroll
        for (int i=0;i<16;i++){
            float m=a2[i]*sc+bi;
            kv[i]=siluf(m)-0.1f*ye[co][v0+i+2];
        }
    }
    __syncthreads();
    #pragma unroll
    for (int i=0;i<16;i++) hs[co][v0+i]=kv[i];
    __syncthreads();

    // epilogue: coalesced global updates from LDS
    float esum=0.f;
    const float dt6=dt/6.0f;
    for (int idx=tid; idx<4096; idx+=256){
        int ci=idx>>6, p=idx&63;
        float k=hs[ci][p];
        size_t gi=(size_t)(b*64+ci)*LSEQ + l0+p;
        if (eval==0){ kout[gi]=k; acc[gi]=k; }
        else if (eval<3){ kout[gi]=k; acc[gi]+=2.0f*k; }
        else {
            float yn=yin[gi]+dt6*(acc[gi]+k);
            yout[gi]=yn;
            esum+=yn*yn;
        }
    }
    if (do_energy){
        for (int o=32;o>0;o>>=1) esum+=__shfl_down(esum,o,64);
        if ((tid&63)==0) red[tid>>6]=esum;
        __syncthreads();
        if (tid==0) atomicAdd(&eoutB[lvl*8+b], red[0]+red[1]+red[2]+red[3]);
    }
}

// ---------------- energy renorm (batched over levels) -----------------------
__global__ __launch_bounds__(256) void scale_kernel(
    const float* __restrict__ y, const float* __restrict__ ein,
    const float* __restrict__ eout, float* __restrict__ o)
{
    int idx = blockIdx.x*256 + threadIdx.x;
    int lb = idx>>17;   // (lvl*8+b), 131072 elems each
    float eo = eout[lb]*(1.0f/131072.0f);
    o[idx] = y[idx]*sqrtf(ein[lb]/(eo+1e-8f));
}

// ---------------- 1x1 attention, detail *= (1+a) in place -------------------
__global__ __launch_bounds__(256) void attn_kernel(
    const float* __restrict__ cur, float* __restrict__ detail,
    const float* __restrict__ a1w, const float* __restrict__ a1b,
    const float* __restrict__ a2w, const float* __restrict__ a2b)
{
    __shared__ float c[64][64];
    __shared__ float hid[16][64];
    const int tid=threadIdx.x, b=blockIdx.y, l0=blockIdx.x*64;
    for (int idx=tid; idx<4096; idx+=256){
        int ci=idx>>6, p=idx&63;
        c[ci][p]=cur[(size_t)(b*64+ci)*LSEQ+l0+p];
    }
    __syncthreads();
    for (int idx=tid; idx<1024; idx+=256){
        int h=idx>>6, p=idx&63;
        float acc=a1b[h];
        const float* W=a1w+h*64;
        for (int ci=0;ci<64;ci++) acc += W[ci]*c[ci][p];
        hid[h][p]=geluf(acc);
    }
    __syncthreads();
    for (int idx=tid; idx<4096; idx+=256){
        int co=idx>>6, p=idx&63;
        float acc=a2b[co];
        const float* W=a2w+co*16;
        #pragma unroll
        for (int h=0;h<16;h++) acc += W[h]*hid[h][p];
        float a=sigf(acc);
        size_t gi=(size_t)(b*64+co)*LSEQ+l0+p;
        detail[gi] *= (1.0f+a);
    }
}

// ---------------- gate conv + residual update -------------------------------
__global__ __launch_bounds__(256) void gate_kernel(
    const float* __restrict__ cur, const float* __restrict__ detail,
    const float* __restrict__ gwt, const float* __restrict__ gb,
    float* __restrict__ curout)
{
    __shared__ float yc[64][66];
    __shared__ float dtile[64][65];
    const int tid=threadIdx.x, b=blockIdx.y, l0=blockIdx.x*64;
    for (int idx=tid; idx<64*66; idx+=256){
        int ci=idx/66, u=idx-ci*66;
        int l=l0+u-1;
        yc[ci][u]=(l>=0 && l<LSEQ)? cur[(size_t)(b*64+ci)*LSEQ+l] : 0.f;
    }
    for (int idx=tid; idx<4096; idx+=256){
        int ci=idx>>6, p=idx&63;
        dtile[ci][p]=detail[(size_t)(b*64+ci)*LSEQ+l0+p];
    }
    __syncthreads();
    const int co=tid&63, g=tid>>6;
    const int p0=g*16;
    float a[16];
    float bb=gb[co];
    #pragma unroll
    for (int i=0;i<16;i++) a[i]=bb;
    for (int ci=0;ci<64;ci++){
        float w0=gwt[(ci*3+0)*64+co];
        float w1_=gwt[(ci*3+1)*64+co];
        float w2_=gwt[(ci*3+2)*64+co];
        float x[18];
        #pragma unroll
        for (int j=0;j<18;j++) x[j]=yc[ci][p0+j];
        #pragma unroll
        for (int i=0;i<16;i++) a[i] += w0*x[i]+w1_*x[i+1]+w2_*x[i+2];
    }
    float r[16];
    #pragma unroll
    for (int i=0;i<16;i++){
        float gt=sigf(a[i]);
        r[i]=yc[co][p0+i+1]+gt*dtile[co][p0+i];
    }
    __syncthreads();
    #pragma unroll
    for (int i=0;i<16;i++) dtile[co][p0+i]=r[i];
    __syncthreads();
    for (int idx=tid; idx<4096; idx+=256){
        int ci=idx>>6, p=idx&63;
        curout[(size_t)(b*64+ci)*LSEQ+l0+p]=dtile[ci][p];
    }
}

extern "C" void kernel_launch(void* const* d_in, const int* in_sizes, int n_in,
                              void* d_out, int out_size, void* d_ws, size_t ws_size,
                              hipStream_t stream)
{
    (void)in_sizes; (void)n_in; (void)out_size; (void)ws_size;
    const float* x       =(const float*)d_in[0];
    const float* dy_w1   =(const float*)d_in[1];
    const float* dy_b1   =(const float*)d_in[2];
    const float* dy_wg1  =(const float*)d_in[3];
    const float* dy_bg1  =(const float*)d_in[4];
    const float* dy_wg2  =(const float*)d_in[5];
    const float* dy_bg2  =(const float*)d_in[6];
    const float* ode_c1w =(const float*)d_in[7];
    const float* ode_c1b =(const float*)d_in[8];
    const float* ode_c2w =(const float*)d_in[9];
    const float* ode_c2b =(const float*)d_in[10];
    const float* ode_wt  =(const float*)d_in[11];
    const float* ode_bt  =(const float*)d_in[12];
    const float* ode_wm  =(const float*)d_in[13];
    const float* ode_bm  =(const float*)d_in[14];
    const float* ode_emb =(const float*)d_in[15];
    const float* gate_w  =(const float*)d_in[16];
    const float* gate_b  =(const float*)d_in[17];
    const float* attn1_w =(const float*)d_in[18];
    const float* attn1_b =(const float*)d_in[19];
    const float* attn2_w =(const float*)d_in[20];
    const float* attn2_b =(const float*)d_in[21];
    float* out=(float*)d_out;
    float* ws=(float*)d_ws;
    const size_t N=NTOT;
    // workspace layout (floats): 20N + ~190K ≈ 85 MB
    float* CB = ws;          // coeff[4]: A0, D1, D2, D3 (4N)
    float* PB = ws+4*N;      // y ping (4 levels) — also decomp temps T0,T1
    float* QB = ws+8*N;      // y pong (4 levels)
    float* K0B= ws+12*N;
    float* K1B= ws+16*N;
    float* SM = ws+20*N;
    float* stat_ws =SM;          // 512
    float* lo_ws   =SM+512;      // 64
    float* hi_ws   =SM+576;      // 64
    float* rowstats=SM+1024;     // 4*512*8 = 16384
    float* ts_ws   =SM+17408;    // 4*8
    float* modsc   =SM+17536;    // 4*576
    float* modbi   =SM+19840;    // 4*576
    float* ein     =SM+22144;    // 32
    float* eoutb   =SM+22176;    // 32
    float* WT      =SM+24576;    // 8*12288 (ode conv weights, transposed)
    float* WTG     =WT+8*12288;  // 3*12288 (gate weights, transposed)
    float* ACCB    =out;         // d_out[0..4N) free until scale_kernel

    dim3 blk(256);

    for (int lvl=0;lvl<4;lvl++){
        wtrans_kernel<<<48,blk,0,stream>>>(ode_c1w+(size_t)lvl*12288, WT+(size_t)(2*lvl)*12288);
        wtrans_kernel<<<48,blk,0,stream>>>(ode_c2w+(size_t)lvl*12288, WT+(size_t)(2*lvl+1)*12288);
    }
    for (int i=0;i<3;i++)
        wtrans_kernel<<<48,blk,0,stream>>>(gate_w+(size_t)i*12288, WTG+(size_t)i*12288);

    // ---- wavelet decomposition (3 levels, sequential) ----
    const float* cura=x;
    float* outsA[3]={PB, PB+N, CB};      // T0, T1, A0-final
    float* outsD[3]={CB+N, CB+2*N, CB+3*N};
    for (int lv=0; lv<3; lv++){
        stat_kernel<<<NROWS,blk,0,stream>>>(cura, stat_ws);
        dywan_kernel<<<1,blk,0,stream>>>(stat_ws, dy_w1,dy_b1,dy_wg1,dy_bg1,dy_wg2,dy_bg2,
                                         lo_ws, hi_ws, out+4*N);
        filt_kernel<<<dim3(8,NROWS),blk,0,stream>>>(cura, lo_ws, hi_ws, outsA[lv], outsD[lv]);
        cura=outsA[lv];
    }

    // ---- adaptive grids + modulation for all 4 levels ----
    tg_pass1<<<dim3(NROWS,4),blk,0,stream>>>(CB, rowstats);
    tg_finalize<<<4,blk,0,stream>>>(rowstats, ode_wt, ode_bt, ode_wm, ode_bm,
                                    ode_emb, ts_ws, modsc, modbi, ein, eoutb);

    // ---- RK4: 16 evals, each batched over 4 levels ----
    const float* yins[4]={CB, PB, QB, PB};
    float*       youts[4]={PB, QB, PB, QB};
    for (int step=0;step<4;step++){
        for (int ev=0;ev<4;ev++){
            const float* kp=(ev==0)?K0B:((ev==1)?K0B:((ev==2)?K1B:K0B));
            float* ko=(ev==0)?K0B:((ev==1)?K1B:((ev==2)?K0B:K0B));
            int doe=(step==3 && ev==3)?1:0;
            ode_eval_all<<<dim3(32,NB,4),blk,0,stream>>>(
                yins[step],kp,ko,ACCB,youts[step],
                WT,ode_c1b,ode_c2b,modsc,modbi,ts_ws,eoutb,step,ev,doe);
        }
    }
    scale_kernel<<<4*NTOT/256,blk,0,stream>>>(QB, ein, eoutb, out);

    // ---- reconstruction ----
    // i=2: current: out0 -> PB; detail = out slot 3 (unchanged)
    gate_kernel<<<dim3(32,NB),blk,0,stream>>>(out+0*N, out+3*N, WTG+2*12288, gate_b+2*64, PB);
    // i=1: attn modifies out slot 2 in place, then gate: PB -> QB
    attn_kernel<<<dim3(32,NB),blk,0,stream>>>(PB, out+2*N, attn1_w+1024, attn1_b+16,
                                              attn2_w+1024, attn2_b+64);
    gate_kernel<<<dim3(32,NB),blk,0,stream>>>(PB, out+2*N, WTG+1*12288, gate_b+64, QB);
    // i=0: attn modifies out slot 1 in place, then gate: QB -> out slot 0
    attn_kernel<<<dim3(32,NB),blk,0,stream>>>(QB, out+1*N, attn1_w, attn1_b,
                                              attn2_w, attn2_b);
    gate_kernel<<<dim3(32,NB),blk,0,stream>>>(QB, out+1*N, WTG, gate_b, out+0*N);
}

// Round 8
// 1023.054 us; speedup vs baseline: 4.3282x; 1.5464x over previous
//
#include <hip/hip_runtime.h>
#include <math.h>

#define LSEQ 2048
#define NB 8
#define NCH 64
#define NTOT (NB*NCH*LSEQ)   // 1048576
#define NROWS (NB*NCH)       // 512

typedef __attribute__((ext_vector_type(8))) short short8;
typedef __attribute__((ext_vector_type(4))) float float4v;

__device__ __forceinline__ float geluf(float x){
    return 0.5f*x*(1.0f+erff(x*0.70710678118654752f));
}
__device__ __forceinline__ float siluf(float x){
    return x/(1.0f+expf(-x));
}
__device__ __forceinline__ float sigf(float x){
    return 1.0f/(1.0f+expf(-x));
}
__device__ __forceinline__ unsigned short f2bf(float f){
    unsigned u=__float_as_uint(f);
    u += 0x7fffu + ((u>>16)&1u);
    return (unsigned short)(u>>16);
}
__device__ __forceinline__ float bf2f(unsigned h){
    return __uint_as_float((h&0xffffu)<<16);
}

// ---------------- weight transpose: w[64][64][3] -> wt[192][64] (gate) ------
__global__ __launch_bounds__(256) void wtrans_kernel(const float* __restrict__ w,
                                                     float* __restrict__ wt){
    int idx = blockIdx.x*256 + threadIdx.x;   // 12288 total
    int j = idx >> 6, co = idx & 63;
    wt[idx] = w[co*192 + j];
}

// ---- ode weight split-prep: WB[lvl][st][hl][tap][co][ci] bf16 --------------
__global__ __launch_bounds__(256) void wprep_kernel(const float* __restrict__ c1w,
                                                    const float* __restrict__ c2w,
                                                    short* __restrict__ WB){
    int idx = blockIdx.x*256 + threadIdx.x;   // 4*2*3*64*64 = 196608
    if (idx >= 196608) return;
    int ci  = idx & 63;
    int co  = (idx>>6) & 63;
    int tap = (idx>>12) % 3;
    int st  = (idx/(3<<12)) & 1;
    int lvl = idx/(6<<12);
    const float* src = (st==0? c1w : c2w);
    float w = src[(size_t)lvl*12288 + co*192 + ci*3 + tap];
    unsigned short hi = f2bf(w);
    float lo = w - bf2f(hi);
    size_t base = ((((size_t)(lvl*2+st)*2+0)*3+tap)*64+co)*64+ci;
    size_t basl = ((((size_t)(lvl*2+st)*2+1)*3+tap)*64+co)*64+ci;
    WB[base] = (short)hi;
    WB[basl] = (short)f2bf(lo);
}

// ---------------- stat = mean over L ----------------------------------------
__global__ __launch_bounds__(256) void stat_kernel(const float* __restrict__ in,
                                                   float* __restrict__ stat){
    int r = blockIdx.x, tid = threadIdx.x;
    const float* p = in + (size_t)r*LSEQ;
    float acc = 0.f;
    for (int i=tid;i<LSEQ;i+=256) acc += p[i];
    for (int o=32;o>0;o>>=1) acc += __shfl_down(acc,o,64);
    __shared__ float red[4];
    if ((tid&63)==0) red[tid>>6]=acc;
    __syncthreads();
    if (tid==0) stat[r] = (red[0]+red[1]+red[2]+red[3])*(1.0f/LSEQ);
}

// ---------------- dywan MLP + filters + ortho -------------------------------
__global__ __launch_bounds__(256) void dywan_kernel(
    const float* __restrict__ stat,
    const float* __restrict__ w1, const float* __restrict__ b1,
    const float* __restrict__ wg1, const float* __restrict__ bg1,
    const float* __restrict__ wg2, const float* __restrict__ bg2,
    float* __restrict__ lo_out, float* __restrict__ hi_out,
    float* __restrict__ ortho_out)
{
    __shared__ float st[512];
    __shared__ float h1s[512];
    __shared__ float h2s[1024];
    __shared__ float fs[112];
    int tid = threadIdx.x;
    for (int i=tid;i<512;i+=256) st[i]=stat[i];
    __syncthreads();
    for (int idx=tid; idx<512; idx+=256){
        int b=idx>>6, j=idx&63;
        float acc=b1[j];
        const float* W=w1+j*64;
        for (int i=0;i<64;i++) acc += st[b*64+i]*W[i];
        h1s[idx]=geluf(acc);
    }
    __syncthreads();
    for (int idx=tid; idx<1024; idx+=256){
        int b=idx>>7, j=idx&127;
        float acc=bg1[j];
        const float* W=wg1+j*64;
        for (int i=0;i<64;i++) acc += h1s[b*64+i]*W[i];
        h2s[idx]=geluf(acc);
    }
    __syncthreads();
    if (tid<112){
        int b=tid/14, j=tid-b*14;
        float acc=bg2[j];
        const float* W=wg2+j*128;
        for (int i=0;i<128;i++) acc += h2s[b*128+i]*W[i];
        fs[tid]=acc;
    }
    __syncthreads();
    if (tid<56){
        int b=tid/7, k=tid-b*7;
        lo_out[tid]=fs[b*14+k];
        hi_out[tid]=fs[b*14+7+k];
    }
    if (tid==0){
        float smooth=0.f, shiftsum=0.f, ampsum=0.f;
        for (int b=0;b<8;b++){
            const float* l = fs + b*14;   // lo row
            float prev=0.f, nrm=0.f;
            for (int k=0;k<7;k++){ smooth += fabsf(l[k]-prev); prev=l[k]; nrm += l[k]*l[k]; }
            smooth += fabsf(prev);
            float denom = sqrtf(nrm) + 1e-8f;
            float sabs=0.f, s2=0.f;
            for (int k=0;k<7;k++){ float v=l[k]/denom; sabs+=fabsf(v); s2+=v*v; }
            shiftsum += sabs*sabs;
            ampsum += fabsf(s2-1.0f);
        }
        smooth *= (1.0f/64.0f);
        float shift = 3.0f*shiftsum/(8.0f*49.0f);
        float amp = ampsum*(1.0f/8.0f);
        *ortho_out = 0.01f*(shift+amp) + 0.1f*smooth;
    }
}

// ---------------- per-batch 7-tap filter conv (edge pad) --------------------
__global__ __launch_bounds__(256) void filt_kernel(
    const float* __restrict__ ap, const float* __restrict__ lo,
    const float* __restrict__ hi, float* __restrict__ na,
    float* __restrict__ det)
{
    int r = blockIdx.y, l0 = blockIdx.x*256, tid = threadIdx.x;
    int b = r>>6;
    __shared__ float s[262];
    __shared__ float fl[7], fh[7];
    for (int idx=tid; idx<262; idx+=256){
        int l = l0+idx-3;
        l = min(max(l,0),LSEQ-1);
        s[idx]=ap[(size_t)r*LSEQ+l];
    }
    if (tid<7) fl[tid]=lo[b*7+tid];
    else if (tid<14) fh[tid-7]=hi[b*7+tid-7];
    __syncthreads();
    float a=0.f, d=0.f;
    #pragma unroll
    for (int k=0;k<7;k++){ float v=s[tid+k]; a+=v*fl[k]; d+=v*fh[k]; }
    na[(size_t)r*LSEQ+l0+tid]=a;
    det[(size_t)r*LSEQ+l0+tid]=d;
}

// ---------------- time grid pass1: per-row stats (batched over levels) ------
__global__ __launch_bounds__(256) void tg_pass1(const float* __restrict__ CB,
                                                float* __restrict__ rowstats){
    __shared__ float sh[2048];
    __shared__ float red[28];
    int r = blockIdx.x, lvl = blockIdx.y, tid = threadIdx.x;
    const float* s = CB + (size_t)lvl*NTOT + (size_t)r*LSEQ;
    float* rso = rowstats + (size_t)(lvl*NROWS+r)*8;
    for (int i=tid;i<2048;i+=256) sh[i]=s[i];
    __syncthreads();
    float ssq=0.f;
    for (int i=tid;i<2048;i+=256){ float v=sh[i]; ssq+=v*v; }
    float mn=1e30f, mx=-1e30f, s0=0.f,s1=0.f,s2=0.f,s3=0.f;
    for (int j=tid;j<2047;j+=256){
        int k0 = (j-2>0)? j-2:0;
        int k1 = (j+2<2046)? j+2:2046;
        float acc=0.f;
        for (int k=k0;k<=k1;k++) acc += fabsf(sh[k+1]-sh[k]);
        float inten = acc*0.2f;
        mn=fminf(mn,inten); mx=fmaxf(mx,inten);
        if (j<511)  s0+=inten;
        if (j<1023) s1+=inten;
        if (j<1534) s2+=inten;
        if (j<2046) s3+=inten;
    }
    float vals[7]={mn,mx,s0,s1,s2,s3,ssq};
    for (int o=32;o>0;o>>=1){
        vals[0]=fminf(vals[0],__shfl_down(vals[0],o,64));
        vals[1]=fmaxf(vals[1],__shfl_down(vals[1],o,64));
        vals[2]+=__shfl_down(vals[2],o,64);
        vals[3]+=__shfl_down(vals[3],o,64);
        vals[4]+=__shfl_down(vals[4],o,64);
        vals[5]+=__shfl_down(vals[5],o,64);
        vals[6]+=__shfl_down(vals[6],o,64);
    }
    int lane=tid&63, w=tid>>6;
    if (lane==0) for (int q=0;q<7;q++) red[w*7+q]=vals[q];
    __syncthreads();
    if (tid==0){
        rso[0]=fminf(fminf(red[0],red[7]),fminf(red[14],red[21]));
        rso[1]=fmaxf(fmaxf(red[1],red[8]),fmaxf(red[15],red[22]));
        rso[2]=red[2]+red[9]+red[16]+red[23];
        rso[3]=red[3]+red[10]+red[17]+red[24];
        rso[4]=red[4]+red[11]+red[18]+red[25];
        rso[5]=red[5]+red[12]+red[19]+red[26];
        rso[6]=red[6]+red[13]+red[20]+red[27];
    }
}

// ---------------- time grid finalize + modulation (grid = 4 levels) ---------
__global__ __launch_bounds__(256) void tg_finalize(
    const float* __restrict__ rowstats,
    const float* __restrict__ wt, const float* __restrict__ bt,
    const float* __restrict__ wm, const float* __restrict__ bm,
    const float* __restrict__ emb,
    float* __restrict__ ts_out, float* __restrict__ modsc,
    float* __restrict__ modbi, float* __restrict__ ein,
    float* __restrict__ eout)
{
    int tid=threadIdx.x;
    const int lvl=blockIdx.x;
    const float* rs = rowstats + (size_t)lvl*NROWS*8;
    __shared__ float red[28];
    __shared__ float stv[9];
    __shared__ float temb[144];
    float mn=1e30f,mx=-1e30f,a0=0.f,a1=0.f,a2=0.f,a3=0.f,m3=-1e30f;
    for (int r=tid;r<512;r+=256){
        mn=fminf(mn,rs[r*8+0]); mx=fmaxf(mx,rs[r*8+1]);
        a0+=rs[r*8+2]; a1+=rs[r*8+3]; a2+=rs[r*8+4]; a3+=rs[r*8+5];
        m3=fmaxf(m3,rs[r*8+5]);
    }
    float vals[7]={mn,mx,a0,a1,a2,a3,m3};
    for (int o=32;o>0;o>>=1){
        vals[0]=fminf(vals[0],__shfl_down(vals[0],o,64));
        vals[1]=fmaxf(vals[1],__shfl_down(vals[1],o,64));
        vals[2]+=__shfl_down(vals[2],o,64);
        vals[3]+=__shfl_down(vals[3],o,64);
        vals[4]+=__shfl_down(vals[4],o,64);
        vals[5]+=__shfl_down(vals[5],o,64);
        vals[6]=fmaxf(vals[6],__shfl_down(vals[6],o,64));
    }
    int lane=tid&63, w=tid>>6;
    if (lane==0) for (int q=0;q<7;q++) red[w*7+q]=vals[q];
    if (tid<8){
        float e=0.f;
        for (int c=0;c<64;c++) e += rs[(tid*64+c)*8+6];
        ein[lvl*8+tid]=e*(1.0f/131072.0f);
        eout[lvl*8+tid]=0.f;
    }
    __syncthreads();
    if (tid==0){
        float mnv=fminf(fminf(red[0],red[7]),fminf(red[14],red[21]));
        float mxv=fmaxf(fmaxf(red[1],red[8]),fmaxf(red[15],red[22]));
        float s0=red[2]+red[9]+red[16]+red[23];
        float s1=red[3]+red[10]+red[17]+red[24];
        float s2=red[4]+red[11]+red[18]+red[25];
        float s3=red[5]+red[12]+red[19]+red[26];
        float m3v=fmaxf(fmaxf(red[6],red[13]),fmaxf(red[20],red[27]));
        const float idxs[5]={0.f,511.f,1023.f,1534.f,2046.f};
        float tsv[5];
        if (mxv-mnv < 1e-8f){
            for (int k=0;k<5;k++) tsv[k]=idxs[k]/2046.0f;
        } else {
            float a = 0.9f/(mxv-mnv+1e-30f);
            float bb = 0.1f - a*mnv;
            float gmax = a*m3v + bb*2046.0f;
            float sums[5]={0.f,s0,s1,s2,s3};
            tsv[0]=0.f;
            for (int k=1;k<5;k++)
                tsv[k]=(a*(sums[k]*(1.0f/512.0f)) + bb*idxs[k])/gmax;
        }
        for (int k=0;k<5;k++){ ts_out[lvl*8+k]=tsv[k]; stv[2*k]=tsv[k]; }
        for (int k=0;k<4;k++) stv[2*k+1]=tsv[k] + 0.5f*(tsv[k+1]-tsv[k]);
    }
    __syncthreads();
    if (tid<144){
        int m=tid>>4, i=tid&15;
        float z = wt[lvl*16+i]*stv[m] + bt[lvl*16+i];
        temb[tid]=siluf(z);
    }
    __syncthreads();
    for (int idx=tid; idx<1152; idx+=256){
        int m=idx>>7, c=idx&127;
        float g=bm[lvl*128+c];
        const float* W=wm+(size_t)(lvl*128+c)*16;
        const float* te=temb+m*16;
        for (int i=0;i<16;i++) g += W[i]*te[i];
        if (c<64) modsc[lvl*576+m*64+c]=1.0f+g+emb[(lvl*8+lvl)*64+c];
        else      modbi[lvl*576+m*64+(c-64)]=g;
    }
}

// ---------------- MFMA fused ode_f eval ------------------------------------
// grid (32, 8, 4): (64-pos tile, batch, level). block 256 = 4 waves.
// Wave wv owns co-tile [16wv,16wv+16). GEMM per tap: D[co][pos] += W_tap * Y_shift.
// Split-bf16: hi*hi + hi*lo + lo*hi ~ fp32. LDS: transposed packed-pair tiles,
// B fragment = one aligned ds_read_b128.
__global__ __launch_bounds__(256) void ode_eval_all(
    const float* __restrict__ yinB, const float* __restrict__ kprevB,
    float* __restrict__ koutB, float* __restrict__ accB,
    float* __restrict__ youtB,
    const short* __restrict__ WB, const float* __restrict__ c1bB,
    const float* __restrict__ c2bB,
    const float* __restrict__ modscB, const float* __restrict__ modbiB,
    const float* __restrict__ tsB, float* __restrict__ eoutB,
    int step, int eval, int do_energy)
{
    __shared__ unsigned yTh[84][36];   // row r <-> ye pos l0-2+r ; packed ci pairs
    __shared__ unsigned yTl[84][36];
    __shared__ unsigned hTh[84][36];   // row r <-> h pos l0-1+r
    __shared__ unsigned hTl[84][36];
    __shared__ float red[4];
    const int tid=threadIdx.x;
    const int lvl=blockIdx.z;
    const int b=blockIdx.y;
    const int l0=blockIdx.x*64;
    const size_t loff=(size_t)lvl*NTOT;
    const float* yin = yinB + loff;
    const float* kprev = kprevB + loff;
    float* kout = koutB + loff;
    float* acc = accB + loff;
    float* yout = youtB + loff;
    const float dt = tsB[lvl*8+step+1]-tsB[lvl*8+step];
    const float alpha=(eval==0)?0.f:((eval==3)?dt:0.5f*dt);
    const int tslot=2*step+((eval==0)?0:((eval==3)?2:1));
    const int wv=tid>>6, lane=tid&63;
    const int n=lane&15, quad=lane>>4;
    const int m0=wv*16;

    // ---- stage ye (+alpha*kprev) into split-bf16 transposed packed tiles ----
    #pragma unroll
    for (int pass=0; pass<2; pass++){
        int r = pass*64 + lane;
        if (r < 84){
            int l = l0 - 2 + r;
            bool ok = (l>=0 && l<LSEQ);
            #pragma unroll
            for (int qq=0; qq<8; qq++){
                int q = wv*8 + qq;
                float v0=0.f, v1=0.f;
                if (ok){
                    size_t g0=(size_t)(b*64+2*q)*LSEQ+l;
                    v0=yin[g0]; v1=yin[g0+LSEQ];
                    if (eval!=0){ v0+=alpha*kprev[g0]; v1+=alpha*kprev[g0+LSEQ]; }
                }
                unsigned short h0=f2bf(v0), h1=f2bf(v1);
                yTh[r][q] = (unsigned)h0 | ((unsigned)h1<<16);
                yTl[r][q] = (unsigned)f2bf(v0-bf2f(h0)) | ((unsigned)f2bf(v1-bf2f(h1))<<16);
            }
        }
    }
    __syncthreads();

    // ---- conv1 (5 n-tiles covering h pos l0-1 .. l0+78) ----
    {
        const short* W1 = WB + (size_t)(lvl*2+0)*2*3*4096;
        short8 A[3][2][2];
        #pragma unroll
        for (int tap=0;tap<3;tap++)
            #pragma unroll
            for (int ks=0;ks<2;ks++)
                #pragma unroll
                for (int hl=0;hl<2;hl++)
                    A[tap][ks][hl] = *(const short8*)(W1 + (((size_t)hl*3+tap)*64 + (m0+n))*64 + ks*32 + quad*8);
        float bia[4];
        #pragma unroll
        for (int reg=0;reg<4;reg++) bia[reg]=c1bB[lvl*64 + m0 + quad*4 + reg];
        const int q0=(m0>>1)+quad*2;
        for (int nt=0; nt<5; nt++){
            float4v d = {bia[0],bia[1],bia[2],bia[3]};
            #pragma unroll
            for (int tap=0;tap<3;tap++){
                const int rr = 16*nt + n + tap;
                const unsigned* ph=&yTh[rr][0];
                const unsigned* pl=&yTl[rr][0];
                #pragma unroll
                for (int ks=0;ks<2;ks++){
                    short8 bh = *(const short8*)(ph + ks*16 + quad*4);
                    short8 bl = *(const short8*)(pl + ks*16 + quad*4);
                    d = __builtin_amdgcn_mfma_f32_16x16x32_bf16(A[tap][ks][0], bh, d, 0,0,0);
                    d = __builtin_amdgcn_mfma_f32_16x16x32_bf16(A[tap][ks][0], bl, d, 0,0,0);
                    d = __builtin_amdgcn_mfma_f32_16x16x32_bf16(A[tap][ks][1], bh, d, 0,0,0);
                }
            }
            int hpos = l0 - 1 + 16*nt + n;
            bool okh = (hpos>=0 && hpos<LSEQ);
            float h0 = okh? geluf(d[0]) : 0.f;
            float h1 = okh? geluf(d[1]) : 0.f;
            float h2 = okh? geluf(d[2]) : 0.f;
            float h3 = okh? geluf(d[3]) : 0.f;
            int rh = 16*nt + n;
            unsigned short c0=f2bf(h0), c1=f2bf(h1), c2=f2bf(h2), c3=f2bf(h3);
            hTh[rh][q0]   = (unsigned)c0 | ((unsigned)c1<<16);
            hTh[rh][q0+1] = (unsigned)c2 | ((unsigned)c3<<16);
            hTl[rh][q0]   = (unsigned)f2bf(h0-bf2f(c0)) | ((unsigned)f2bf(h1-bf2f(c1))<<16);
            hTl[rh][q0+1] = (unsigned)f2bf(h2-bf2f(c2)) | ((unsigned)f2bf(h3-bf2f(c3))<<16);
        }
    }
    __syncthreads();

    // ---- conv2 (4 n-tiles, output pos l0 .. l0+63) ----
    float esum=0.f;
    {
        const short* W2 = WB + (size_t)(lvl*2+1)*2*3*4096;
        short8 A[3][2][2];
        #pragma unroll
        for (int tap=0;tap<3;tap++)
            #pragma unroll
            for (int ks=0;ks<2;ks++)
                #pragma unroll
                for (int hl=0;hl<2;hl++)
                    A[tap][ks][hl] = *(const short8*)(W2 + (((size_t)hl*3+tap)*64 + (m0+n))*64 + ks*32 + quad*8);
        float bib[4], sc[4], bi2[4];
        #pragma unroll
        for (int reg=0;reg<4;reg++){
            int co = m0 + quad*4 + reg;
            bib[reg]=c2bB[lvl*64+co];
            sc[reg]=modscB[lvl*576+tslot*64+co];
            bi2[reg]=modbiB[lvl*576+tslot*64+co];
        }
        const float dt6 = dt/6.0f;
        const int qy0=(m0+quad*4)>>1;
        for (int nt=0; nt<4; nt++){
            float4v d = {bib[0],bib[1],bib[2],bib[3]};
            #pragma unroll
            for (int tap=0;tap<3;tap++){
                const int rr = 16*nt + n + tap;
                const unsigned* ph=&hTh[rr][0];
                const unsigned* pl=&hTl[rr][0];
                #pragma unroll
                for (int ks=0;ks<2;ks++){
                    short8 bh = *(const short8*)(ph + ks*16 + quad*4);
                    short8 bl = *(const short8*)(pl + ks*16 + quad*4);
                    d = __builtin_amdgcn_mfma_f32_16x16x32_bf16(A[tap][ks][0], bh, d, 0,0,0);
                    d = __builtin_amdgcn_mfma_f32_16x16x32_bf16(A[tap][ks][0], bl, d, 0,0,0);
                    d = __builtin_amdgcn_mfma_f32_16x16x32_bf16(A[tap][ks][1], bh, d, 0,0,0);
                }
            }
            int p = l0 + 16*nt + n;
            int ry = 16*nt + n + 2;
            unsigned uh0=yTh[ry][qy0],   ul0=yTl[ry][qy0];
            unsigned uh1=yTh[ry][qy0+1], ul1=yTl[ry][qy0+1];
            float yev[4];
            yev[0]=bf2f(uh0)+bf2f(ul0);
            yev[1]=bf2f(uh0>>16)+bf2f(ul0>>16);
            yev[2]=bf2f(uh1)+bf2f(ul1);
            yev[3]=bf2f(uh1>>16)+bf2f(ul1>>16);
            size_t gbase=(size_t)(b*64 + m0 + quad*4)*LSEQ + p;
            #pragma unroll
            for (int reg=0;reg<4;reg++){
                float m = d[reg]*sc[reg] + bi2[reg];
                float kv = siluf(m) - 0.1f*yev[reg];
                size_t gi = gbase + (size_t)reg*LSEQ;
                if (eval==0){ kout[gi]=kv; acc[gi]=kv; }
                else if (eval<3){ kout[gi]=kv; acc[gi]+=2.0f*kv; }
                else {
                    float yn = yin[gi] + dt6*(acc[gi]+kv);
                    yout[gi]=yn;
                    esum += yn*yn;
                }
            }
        }
    }
    if (do_energy){
        for (int o=32;o>0;o>>=1) esum+=__shfl_down(esum,o,64);
        if ((tid&63)==0) red[tid>>6]=esum;
        __syncthreads();
        if (tid==0) atomicAdd(&eoutB[lvl*8+b], red[0]+red[1]+red[2]+red[3]);
    }
}

// ---------------- energy renorm (batched over levels) -----------------------
__global__ __launch_bounds__(256) void scale_kernel(
    const float* __restrict__ y, const float* __restrict__ ein,
    const float* __restrict__ eout, float* __restrict__ o)
{
    int idx = blockIdx.x*256 + threadIdx.x;
    int lb = idx>>17;   // (lvl*8+b), 131072 elems each
    float eo = eout[lb]*(1.0f/131072.0f);
    o[idx] = y[idx]*sqrtf(ein[lb]/(eo+1e-8f));
}

// ---------------- 1x1 attention, detail *= (1+a) in place -------------------
__global__ __launch_bounds__(256) void attn_kernel(
    const float* __restrict__ cur, float* __restrict__ detail,
    const float* __restrict__ a1w, const float* __restrict__ a1b,
    const float* __restrict__ a2w, const float* __restrict__ a2b)
{
    __shared__ float c[64][64];
    __shared__ float hid[16][64];
    const int tid=threadIdx.x, b=blockIdx.y, l0=blockIdx.x*64;
    for (int idx=tid; idx<4096; idx+=256){
        int ci=idx>>6, p=idx&63;
        c[ci][p]=cur[(size_t)(b*64+ci)*LSEQ+l0+p];
    }
    __syncthreads();
    for (int idx=tid; idx<1024; idx+=256){
        int h=idx>>6, p=idx&63;
        float acc=a1b[h];
        const float* W=a1w+h*64;
        for (int ci=0;ci<64;ci++) acc += W[ci]*c[ci][p];
        hid[h][p]=geluf(acc);
    }
    __syncthreads();
    for (int idx=tid; idx<4096; idx+=256){
        int co=idx>>6, p=idx&63;
        float acc=a2b[co];
        const float* W=a2w+co*16;
        #pragma unroll
        for (int h=0;h<16;h++) acc += W[h]*hid[h][p];
        float a=sigf(acc);
        size_t gi=(size_t)(b*64+co)*LSEQ+l0+p;
        detail[gi] *= (1.0f+a);
    }
}

// ---------------- gate conv + residual update -------------------------------
__global__ __launch_bounds__(256) void gate_kernel(
    const float* __restrict__ cur, const float* __restrict__ detail,
    const float* __restrict__ gwt, const float* __restrict__ gb,
    float* __restrict__ curout)
{
    __shared__ float yc[64][66];
    __shared__ float dtile[64][65];
    const int tid=threadIdx.x, b=blockIdx.y, l0=blockIdx.x*64;
    for (int idx=tid; idx<64*66; idx+=256){
        int ci=idx/66, u=idx-ci*66;
        int l=l0+u-1;
        yc[ci][u]=(l>=0 && l<LSEQ)? cur[(size_t)(b*64+ci)*LSEQ+l] : 0.f;
    }
    for (int idx=tid; idx<4096; idx+=256){
        int ci=idx>>6, p=idx&63;
        dtile[ci][p]=detail[(size_t)(b*64+ci)*LSEQ+l0+p];
    }
    __syncthreads();
    const int co=tid&63, g=tid>>6;
    const int p0=g*16;
    float a[16];
    float bb=gb[co];
    #pragma unroll
    for (int i=0;i<16;i++) a[i]=bb;
    for (int ci=0;ci<64;ci++){
        float w0=gwt[(ci*3+0)*64+co];
        float w1_=gwt[(ci*3+1)*64+co];
        float w2_=gwt[(ci*3+2)*64+co];
        float x[18];
        #pragma unroll
        for (int j=0;j<18;j++) x[j]=yc[ci][p0+j];
        #pragma unroll
        for (int i=0;i<16;i++) a[i] += w0*x[i]+w1_*x[i+1]+w2_*x[i+2];
    }
    float r[16];
    #pragma unroll
    for (int i=0;i<16;i++){
        float gt=sigf(a[i]);
        r[i]=yc[co][p0+i+1]+gt*dtile[co][p0+i];
    }
    __syncthreads();
    #pragma unroll
    for (int i=0;i<16;i++) dtile[co][p0+i]=r[i];
    __syncthreads();
    for (int idx=tid; idx<4096; idx+=256){
        int ci=idx>>6, p=idx&63;
        curout[(size_t)(b*64+ci)*LSEQ+l0+p]=dtile[ci][p];
    }
}

extern "C" void kernel_launch(void* const* d_in, const int* in_sizes, int n_in,
                              void* d_out, int out_size, void* d_ws, size_t ws_size,
                              hipStream_t stream)
{
    (void)in_sizes; (void)n_in; (void)out_size; (void)ws_size;
    const float* x       =(const float*)d_in[0];
    const float* dy_w1   =(const float*)d_in[1];
    const float* dy_b1   =(const float*)d_in[2];
    const float* dy_wg1  =(const float*)d_in[3];
    const float* dy_bg1  =(const float*)d_in[4];
    const float* dy_wg2  =(const float*)d_in[5];
    const float* dy_bg2  =(const float*)d_in[6];
    const float* ode_c1w =(const float*)d_in[7];
    const float* ode_c1b =(const float*)d_in[8];
    const float* ode_c2w =(const float*)d_in[9];
    const float* ode_c2b =(const float*)d_in[10];
    const float* ode_wt  =(const float*)d_in[11];
    const float* ode_bt  =(const float*)d_in[12];
    const float* ode_wm  =(const float*)d_in[13];
    const float* ode_bm  =(const float*)d_in[14];
    const float* ode_emb =(const float*)d_in[15];
    const float* gate_w  =(const float*)d_in[16];
    const float* gate_b  =(const float*)d_in[17];
    const float* attn1_w =(const float*)d_in[18];
    const float* attn1_b =(const float*)d_in[19];
    const float* attn2_w =(const float*)d_in[20];
    const float* attn2_b =(const float*)d_in[21];
    float* out=(float*)d_out;
    float* ws=(float*)d_ws;
    const size_t N=NTOT;
    // workspace layout (floats): 20N + ~260K ≈ 85 MB
    float* CB = ws;          // coeff[4]: A0, D1, D2, D3 (4N)
    float* PB = ws+4*N;      // y ping (4 levels) — also decomp temps T0,T1
    float* QB = ws+8*N;      // y pong (4 levels)
    float* K0B= ws+12*N;
    float* K1B= ws+16*N;
    float* SM = ws+20*N;
    float* stat_ws =SM;          // 512
    float* lo_ws   =SM+512;      // 64
    float* hi_ws   =SM+576;      // 64
    float* rowstats=SM+1024;     // 4*512*8 = 16384
    float* ts_ws   =SM+17408;    // 4*8
    float* modsc   =SM+17536;    // 4*576
    float* modbi   =SM+19840;    // 4*576
    float* ein     =SM+22144;    // 32
    float* eoutb   =SM+22176;    // 32
    short* WB      =(short*)(SM+24576);  // 393216 bf16 = 196608 floats
    float* WTG     =SM+24576+196608;     // 3*12288 (gate weights, transposed)
    float* ACCB    =out;         // d_out[0..4N) free until scale_kernel

    dim3 blk(256);

    wprep_kernel<<<768,blk,0,stream>>>(ode_c1w, ode_c2w, WB);
    for (int i=0;i<3;i++)
        wtrans_kernel<<<48,blk,0,stream>>>(gate_w+(size_t)i*12288, WTG+(size_t)i*12288);

    // ---- wavelet decomposition (3 levels, sequential) ----
    const float* cura=x;
    float* outsA[3]={PB, PB+N, CB};      // T0, T1, A0-final
    float* outsD[3]={CB+N, CB+2*N, CB+3*N};
    for (int lv=0; lv<3; lv++){
        stat_kernel<<<NROWS,blk,0,stream>>>(cura, stat_ws);
        dywan_kernel<<<1,blk,0,stream>>>(stat_ws, dy_w1,dy_b1,dy_wg1,dy_bg1,dy_wg2,dy_bg2,
                                         lo_ws, hi_ws, out+4*N);
        filt_kernel<<<dim3(8,NROWS),blk,0,stream>>>(cura, lo_ws, hi_ws, outsA[lv], outsD[lv]);
        cura=outsA[lv];
    }

    // ---- adaptive grids + modulation for all 4 levels ----
    tg_pass1<<<dim3(NROWS,4),blk,0,stream>>>(CB, rowstats);
    tg_finalize<<<4,blk,0,stream>>>(rowstats, ode_wt, ode_bt, ode_wm, ode_bm,
                                    ode_emb, ts_ws, modsc, modbi, ein, eoutb);

    // ---- RK4: 16 evals, each batched over 4 levels ----
    const float* yins[4]={CB, PB, QB, PB};
    float*       youts[4]={PB, QB, PB, QB};
    for (int step=0;step<4;step++){
        for (int ev=0;ev<4;ev++){
            const float* kp=(ev==0)?K0B:((ev==1)?K0B:((ev==2)?K1B:K0B));
            float* ko=(ev==0)?K0B:((ev==1)?K1B:((ev==2)?K0B:K0B));
            int doe=(step==3 && ev==3)?1:0;
            ode_eval_all<<<dim3(32,NB,4),blk,0,stream>>>(
                yins[step],kp,ko,ACCB,youts[step],
                WB,ode_c1b,ode_c2b,modsc,modbi,ts_ws,eoutb,step,ev,doe);
        }
    }
    scale_kernel<<<4*NTOT/256,blk,0,stream>>>(QB, ein, eoutb, out);

    // ---- reconstruction ----
    // i=2: current: out0 -> PB; detail = out slot 3 (unchanged)
    gate_kernel<<<dim3(32,NB),blk,0,stream>>>(out+0*N, out+3*N, WTG+2*12288, gate_b+2*64, PB);
    // i=1: attn modifies out slot 2 in place, then gate: PB -> QB
    attn_kernel<<<dim3(32,NB),blk,0,stream>>>(PB, out+2*N, attn1_w+1024, attn1_b+16,
                                              attn2_w+1024, attn2_b+64);
    gate_kernel<<<dim3(32,NB),blk,0,stream>>>(PB, out+2*N, WTG+1*12288, gate_b+64, QB);
    // i=0: attn modifies out slot 1 in place, then gate: QB -> out slot 0
    attn_kernel<<<dim3(32,NB),blk,0,stream>>>(QB, out+1*N, attn1_w, attn1_b,
                                              attn2_w, attn2_b);
    gate_kernel<<<dim3(32,NB),blk,0,stream>>>(QB, out+1*N, WTG, gate_b, out+0*N);
}

// Round 10
// 834.682 us; speedup vs baseline: 5.3050x; 1.2257x over previous
//
#include <hip/hip_runtime.h>
#include <math.h>

#define LSEQ 2048
#define NB 8
#define NCH 64
#define NTOT (NB*NCH*LSEQ)   // 1048576
#define NROWS (NB*NCH)       // 512

typedef __attribute__((ext_vector_type(8))) short short8;
typedef __attribute__((ext_vector_type(4))) float float4v;

__device__ __forceinline__ float geluf(float x){
    return 0.5f*x*(1.0f+erff(x*0.70710678118654752f));
}
__device__ __forceinline__ float siluf(float x){
    return x/(1.0f+expf(-x));
}
__device__ __forceinline__ float sigf(float x){
    return 1.0f/(1.0f+expf(-x));
}
__device__ __forceinline__ unsigned short f2bf(float f){
    unsigned u=__float_as_uint(f);
    u += 0x7fffu + ((u>>16)&1u);
    return (unsigned short)(u>>16);
}
__device__ __forceinline__ float bf2f(unsigned h){
    return __uint_as_float((h&0xffffu)<<16);
}

// ---------------- weight transpose: w[64][64][3] -> wt[192][64] (gate) ------
__global__ __launch_bounds__(256) void wtrans_kernel(const float* __restrict__ w,
                                                     float* __restrict__ wt){
    int idx = blockIdx.x*256 + threadIdx.x;   // 12288 total
    int j = idx >> 6, co = idx & 63;
    wt[idx] = w[co*192 + j];
}

// ---- ode weight split-prep: WB[lvl][st][hl][tap][co][ci] bf16 --------------
__global__ __launch_bounds__(256) void wprep_kernel(const float* __restrict__ c1w,
                                                    const float* __restrict__ c2w,
                                                    short* __restrict__ WB){
    int idx = blockIdx.x*256 + threadIdx.x;   // 4*2*3*64*64 = 196608
    if (idx >= 196608) return;
    int ci  = idx & 63;
    int co  = (idx>>6) & 63;
    int tap = (idx>>12) % 3;
    int st  = (idx/(3<<12)) & 1;
    int lvl = idx/(6<<12);
    const float* src = (st==0? c1w : c2w);
    float w = src[(size_t)lvl*12288 + co*192 + ci*3 + tap];
    unsigned short hi = f2bf(w);
    float lo = w - bf2f(hi);
    size_t base = ((((size_t)(lvl*2+st)*2+0)*3+tap)*64+co)*64+ci;
    size_t basl = ((((size_t)(lvl*2+st)*2+1)*3+tap)*64+co)*64+ci;
    WB[base] = (short)hi;
    WB[basl] = (short)f2bf(lo);
}

// ---------------- stat = mean over L ----------------------------------------
__global__ __launch_bounds__(256) void stat_kernel(const float* __restrict__ in,
                                                   float* __restrict__ stat){
    int r = blockIdx.x, tid = threadIdx.x;
    const float* p = in + (size_t)r*LSEQ;
    float acc = 0.f;
    for (int i=tid;i<LSEQ;i+=256) acc += p[i];
    for (int o=32;o>0;o>>=1) acc += __shfl_down(acc,o,64);
    __shared__ float red[4];
    if ((tid&63)==0) red[tid>>6]=acc;
    __syncthreads();
    if (tid==0) stat[r] = (red[0]+red[1]+red[2]+red[3])*(1.0f/LSEQ);
}

// ---------------- dywan MLP + filters + ortho -------------------------------
__global__ __launch_bounds__(256) void dywan_kernel(
    const float* __restrict__ stat,
    const float* __restrict__ w1, const float* __restrict__ b1,
    const float* __restrict__ wg1, const float* __restrict__ bg1,
    const float* __restrict__ wg2, const float* __restrict__ bg2,
    float* __restrict__ lo_out, float* __restrict__ hi_out,
    float* __restrict__ ortho_out)
{
    __shared__ float st[512];
    __shared__ float h1s[512];
    __shared__ float h2s[1024];
    __shared__ float fs[112];
    int tid = threadIdx.x;
    for (int i=tid;i<512;i+=256) st[i]=stat[i];
    __syncthreads();
    for (int idx=tid; idx<512; idx+=256){
        int b=idx>>6, j=idx&63;
        float acc=b1[j];
        const float* W=w1+j*64;
        for (int i=0;i<64;i++) acc += st[b*64+i]*W[i];
        h1s[idx]=geluf(acc);
    }
    __syncthreads();
    for (int idx=tid; idx<1024; idx+=256){
        int b=idx>>7, j=idx&127;
        float acc=bg1[j];
        const float* W=wg1+j*64;
        for (int i=0;i<64;i++) acc += h1s[b*64+i]*W[i];
        h2s[idx]=geluf(acc);
    }
    __syncthreads();
    if (tid<112){
        int b=tid/14, j=tid-b*14;
        float acc=bg2[j];
        const float* W=wg2+j*128;
        for (int i=0;i<128;i++) acc += h2s[b*128+i]*W[i];
        fs[tid]=acc;
    }
    __syncthreads();
    if (tid<56){
        int b=tid/7, k=tid-b*7;
        lo_out[tid]=fs[b*14+k];
        hi_out[tid]=fs[b*14+7+k];
    }
    if (tid==0){
        float smooth=0.f, shiftsum=0.f, ampsum=0.f;
        for (int b=0;b<8;b++){
            const float* l = fs + b*14;   // lo row
            float prev=0.f, nrm=0.f;
            for (int k=0;k<7;k++){ smooth += fabsf(l[k]-prev); prev=l[k]; nrm += l[k]*l[k]; }
            smooth += fabsf(prev);
            float denom = sqrtf(nrm) + 1e-8f;
            float sabs=0.f, s2=0.f;
            for (int k=0;k<7;k++){ float v=l[k]/denom; sabs+=fabsf(v); s2+=v*v; }
            shiftsum += sabs*sabs;
            ampsum += fabsf(s2-1.0f);
        }
        smooth *= (1.0f/64.0f);
        float shift = 3.0f*shiftsum/(8.0f*49.0f);
        float amp = ampsum*(1.0f/8.0f);
        *ortho_out = 0.01f*(shift+amp) + 0.1f*smooth;
    }
}

// ---------------- per-batch 7-tap filter conv (edge pad) --------------------
__global__ __launch_bounds__(256) void filt_kernel(
    const float* __restrict__ ap, const float* __restrict__ lo,
    const float* __restrict__ hi, float* __restrict__ na,
    float* __restrict__ det)
{
    int r = blockIdx.y, l0 = blockIdx.x*256, tid = threadIdx.x;
    int b = r>>6;
    __shared__ float s[262];
    __shared__ float fl[7], fh[7];
    for (int idx=tid; idx<262; idx+=256){
        int l = l0+idx-3;
        l = min(max(l,0),LSEQ-1);
        s[idx]=ap[(size_t)r*LSEQ+l];
    }
    if (tid<7) fl[tid]=lo[b*7+tid];
    else if (tid<14) fh[tid-7]=hi[b*7+tid-7];
    __syncthreads();
    float a=0.f, d=0.f;
    #pragma unroll
    for (int k=0;k<7;k++){ float v=s[tid+k]; a+=v*fl[k]; d+=v*fh[k]; }
    na[(size_t)r*LSEQ+l0+tid]=a;
    det[(size_t)r*LSEQ+l0+tid]=d;
}

// ---------------- time grid pass1: per-row stats (batched over levels) ------
__global__ __launch_bounds__(256) void tg_pass1(const float* __restrict__ CB,
                                                float* __restrict__ rowstats){
    __shared__ float sh[2048];
    __shared__ float red[28];
    int r = blockIdx.x, lvl = blockIdx.y, tid = threadIdx.x;
    const float* s = CB + (size_t)lvl*NTOT + (size_t)r*LSEQ;
    float* rso = rowstats + (size_t)(lvl*NROWS+r)*8;
    for (int i=tid;i<2048;i+=256) sh[i]=s[i];
    __syncthreads();
    float ssq=0.f;
    for (int i=tid;i<2048;i+=256){ float v=sh[i]; ssq+=v*v; }
    float mn=1e30f, mx=-1e30f, s0=0.f,s1=0.f,s2=0.f,s3=0.f;
    for (int j=tid;j<2047;j+=256){
        int k0 = (j-2>0)? j-2:0;
        int k1 = (j+2<2046)? j+2:2046;
        float acc=0.f;
        for (int k=k0;k<=k1;k++) acc += fabsf(sh[k+1]-sh[k]);
        float inten = acc*0.2f;
        mn=fminf(mn,inten); mx=fmaxf(mx,inten);
        if (j<511)  s0+=inten;
        if (j<1023) s1+=inten;
        if (j<1534) s2+=inten;
        if (j<2046) s3+=inten;
    }
    float vals[7]={mn,mx,s0,s1,s2,s3,ssq};
    for (int o=32;o>0;o>>=1){
        vals[0]=fminf(vals[0],__shfl_down(vals[0],o,64));
        vals[1]=fmaxf(vals[1],__shfl_down(vals[1],o,64));
        vals[2]+=__shfl_down(vals[2],o,64);
        vals[3]+=__shfl_down(vals[3],o,64);
        vals[4]+=__shfl_down(vals[4],o,64);
        vals[5]+=__shfl_down(vals[5],o,64);
        vals[6]+=__shfl_down(vals[6],o,64);
    }
    int lane=tid&63, w=tid>>6;
    if (lane==0) for (int q=0;q<7;q++) red[w*7+q]=vals[q];
    __syncthreads();
    if (tid==0){
        rso[0]=fminf(fminf(red[0],red[7]),fminf(red[14],red[21]));
        rso[1]=fmaxf(fmaxf(red[1],red[8]),fmaxf(red[15],red[22]));
        rso[2]=red[2]+red[9]+red[16]+red[23];
        rso[3]=red[3]+red[10]+red[17]+red[24];
        rso[4]=red[4]+red[11]+red[18]+red[25];
        rso[5]=red[5]+red[12]+red[19]+red[26];
        rso[6]=red[6]+red[13]+red[20]+red[27];
    }
}

// ---------------- time grid finalize + modulation (grid = 4 levels) ---------
__global__ __launch_bounds__(256) void tg_finalize(
    const float* __restrict__ rowstats,
    const float* __restrict__ wt, const float* __restrict__ bt,
    const float* __restrict__ wm, const float* __restrict__ bm,
    const float* __restrict__ emb,
    float* __restrict__ ts_out, float* __restrict__ modsc,
    float* __restrict__ modbi, float* __restrict__ ein,
    float* __restrict__ eout)
{
    int tid=threadIdx.x;
    const int lvl=blockIdx.x;
    const float* rs = rowstats + (size_t)lvl*NROWS*8;
    __shared__ float red[28];
    __shared__ float stv[9];
    __shared__ float temb[144];
    float mn=1e30f,mx=-1e30f,a0=0.f,a1=0.f,a2=0.f,a3=0.f,m3=-1e30f;
    for (int r=tid;r<512;r+=256){
        mn=fminf(mn,rs[r*8+0]); mx=fmaxf(mx,rs[r*8+1]);
        a0+=rs[r*8+2]; a1+=rs[r*8+3]; a2+=rs[r*8+4]; a3+=rs[r*8+5];
        m3=fmaxf(m3,rs[r*8+5]);
    }
    float vals[7]={mn,mx,a0,a1,a2,a3,m3};
    for (int o=32;o>0;o>>=1){
        vals[0]=fminf(vals[0],__shfl_down(vals[0],o,64));
        vals[1]=fmaxf(vals[1],__shfl_down(vals[1],o,64));
        vals[2]+=__shfl_down(vals[2],o,64);
        vals[3]+=__shfl_down(vals[3],o,64);
        vals[4]+=__shfl_down(vals[4],o,64);
        vals[5]+=__shfl_down(vals[5],o,64);
        vals[6]=fmaxf(vals[6],__shfl_down(vals[6],o,64));
    }
    int lane=tid&63, w=tid>>6;
    if (lane==0) for (int q=0;q<7;q++) red[w*7+q]=vals[q];
    if (tid<8){
        float e=0.f;
        for (int c=0;c<64;c++) e += rs[(tid*64+c)*8+6];
        ein[lvl*8+tid]=e*(1.0f/131072.0f);
        eout[lvl*8+tid]=0.f;
    }
    __syncthreads();
    if (tid==0){
        float mnv=fminf(fminf(red[0],red[7]),fminf(red[14],red[21]));
        float mxv=fmaxf(fmaxf(red[1],red[8]),fmaxf(red[15],red[22]));
        float s0=red[2]+red[9]+red[16]+red[23];
        float s1=red[3]+red[10]+red[17]+red[24];
        float s2=red[4]+red[11]+red[18]+red[25];
        float s3=red[5]+red[12]+red[19]+red[26];
        float m3v=fmaxf(fmaxf(red[6],red[13]),fmaxf(red[20],red[27]));
        const float idxs[5]={0.f,511.f,1023.f,1534.f,2046.f};
        float tsv[5];
        if (mxv-mnv < 1e-8f){
            for (int k=0;k<5;k++) tsv[k]=idxs[k]/2046.0f;
        } else {
            float a = 0.9f/(mxv-mnv+1e-30f);
            float bb = 0.1f - a*mnv;
            float gmax = a*m3v + bb*2046.0f;
            float sums[5]={0.f,s0,s1,s2,s3};
            tsv[0]=0.f;
            for (int k=1;k<5;k++)
                tsv[k]=(a*(sums[k]*(1.0f/512.0f)) + bb*idxs[k])/gmax;
        }
        for (int k=0;k<5;k++){ ts_out[lvl*8+k]=tsv[k]; stv[2*k]=tsv[k]; }
        for (int k=0;k<4;k++) stv[2*k+1]=tsv[k] + 0.5f*(tsv[k+1]-tsv[k]);
    }
    __syncthreads();
    if (tid<144){
        int m=tid>>4, i=tid&15;
        float z = wt[lvl*16+i]*stv[m] + bt[lvl*16+i];
        temb[tid]=siluf(z);
    }
    __syncthreads();
    for (int idx=tid; idx<1152; idx+=256){
        int m=idx>>7, c=idx&127;
        float g=bm[lvl*128+c];
        const float* W=wm+(size_t)(lvl*128+c)*16;
        const float* te=temb+m*16;
        for (int i=0;i<16;i++) g += W[i]*te[i];
        if (c<64) modsc[lvl*576+m*64+c]=1.0f+g+emb[(lvl*8+lvl)*64+c];
        else      modbi[lvl*576+m*64+(c-64)]=g;
    }
}

// ---------------- MFMA fused ode_f eval (reduced LDS: 28.4 KB) --------------
// grid (32, 8, 4): (64-pos tile, batch, level). block 256 = 4 waves.
// conv1: 3-term split (y hi+lo). conv2: 2-term (Whi+Wlo)*h_hi, h stored hi-only.
__global__ __launch_bounds__(256) void ode_eval_all(
    const float* __restrict__ yinB, const float* __restrict__ kprevB,
    float* __restrict__ koutB, float* __restrict__ accB,
    float* __restrict__ youtB,
    const short* __restrict__ WB, const float* __restrict__ c1bB,
    const float* __restrict__ c2bB,
    const float* __restrict__ modscB, const float* __restrict__ modbiB,
    const float* __restrict__ tsB, float* __restrict__ eoutB,
    int step, int eval, int do_energy)
{
    __shared__ unsigned yTh[68][36];   // row r <-> ye pos l0-2+r ; packed ci pairs
    __shared__ unsigned yTl[68][36];
    __shared__ unsigned hTh[66][36];   // row r <-> h pos l0-1+r (hi only)
    __shared__ float red[4];
    const int tid=threadIdx.x;
    const int lvl=blockIdx.z;
    const int b=blockIdx.y;
    const int l0=blockIdx.x*64;
    const size_t loff=(size_t)lvl*NTOT;
    const float* yin = yinB + loff;
    const float* kprev = kprevB + loff;
    float* kout = koutB + loff;
    float* acc = accB + loff;
    float* yout = youtB + loff;
    const float dt = tsB[lvl*8+step+1]-tsB[lvl*8+step];
    const float alpha=(eval==0)?0.f:((eval==3)?dt:0.5f*dt);
    const int tslot=2*step+((eval==0)?0:((eval==3)?2:1));
    const int wv=tid>>6, lane=tid&63;
    const int n=lane&15, quad=lane>>4;
    const int m0=wv*16;

    // ---- stage ye (+alpha*kprev) into split-bf16 transposed tiles ----
    #pragma unroll
    for (int pass=0; pass<2; pass++){
        int r = pass*64 + lane;
        if (r < 68){
            int l = l0 - 2 + r;
            bool ok = (l>=0 && l<LSEQ);
            #pragma unroll
            for (int qq=0; qq<8; qq++){
                int q = wv*8 + qq;
                float v0=0.f, v1=0.f;
                if (ok){
                    size_t g0=(size_t)(b*64+2*q)*LSEQ+l;
                    v0=yin[g0]; v1=yin[g0+LSEQ];
                    if (eval!=0){ v0+=alpha*kprev[g0]; v1+=alpha*kprev[g0+LSEQ]; }
                }
                unsigned short h0=f2bf(v0), h1=f2bf(v1);
                yTh[r][q] = (unsigned)h0 | ((unsigned)h1<<16);
                yTl[r][q] = (unsigned)f2bf(v0-bf2f(h0)) | ((unsigned)f2bf(v1-bf2f(h1))<<16);
            }
        }
    }
    __syncthreads();

    // ---- conv1: h pos l0-1..l0+64 (5 n-tiles; tile 4 only n<2 stored) ----
    {
        const short* W1 = WB + (size_t)(lvl*2+0)*2*3*4096;
        short8 A[3][2][2];
        #pragma unroll
        for (int tap=0;tap<3;tap++)
            #pragma unroll
            for (int ks=0;ks<2;ks++)
                #pragma unroll
                for (int hl=0;hl<2;hl++)
                    A[tap][ks][hl] = *(const short8*)(W1 + (((size_t)hl*3+tap)*64 + (m0+n))*64 + ks*32 + quad*8);
        float bia[4];
        #pragma unroll
        for (int reg=0;reg<4;reg++) bia[reg]=c1bB[lvl*64 + m0 + quad*4 + reg];
        const int q0=(m0>>1)+quad*2;
        for (int nt=0; nt<5; nt++){
            float4v d = {bia[0],bia[1],bia[2],bia[3]};
            #pragma unroll
            for (int tap=0;tap<3;tap++){
                int rr = 16*nt + n + tap;
                rr = (rr>67)? 67 : rr;           // clamp (junk rows unused)
                const unsigned* ph=&yTh[rr][0];
                const unsigned* pl=&yTl[rr][0];
                #pragma unroll
                for (int ks=0;ks<2;ks++){
                    short8 bh = *(const short8*)(ph + ks*16 + quad*4);
                    short8 bl = *(const short8*)(pl + ks*16 + quad*4);
                    d = __builtin_amdgcn_mfma_f32_16x16x32_bf16(A[tap][ks][0], bh, d, 0,0,0);
                    d = __builtin_amdgcn_mfma_f32_16x16x32_bf16(A[tap][ks][0], bl, d, 0,0,0);
                    d = __builtin_amdgcn_mfma_f32_16x16x32_bf16(A[tap][ks][1], bh, d, 0,0,0);
                }
            }
            if (nt<4 || n<2){
                int rh = 16*nt + n;
                int hpos = l0 - 1 + rh;
                bool okh = (hpos>=0 && hpos<LSEQ);
                float h0 = okh? geluf(d[0]) : 0.f;
                float h1 = okh? geluf(d[1]) : 0.f;
                float h2 = okh? geluf(d[2]) : 0.f;
                float h3 = okh? geluf(d[3]) : 0.f;
                hTh[rh][q0]   = (unsigned)f2bf(h0) | ((unsigned)f2bf(h1)<<16);
                hTh[rh][q0+1] = (unsigned)f2bf(h2) | ((unsigned)f2bf(h3)<<16);
            }
        }
    }
    __syncthreads();

    // ---- conv2 (4 n-tiles, output pos l0..l0+63) + epilogue ----
    float esum=0.f;
    {
        const short* W2 = WB + (size_t)(lvl*2+1)*2*3*4096;
        short8 A[3][2][2];
        #pragma unroll
        for (int tap=0;tap<3;tap++)
            #pragma unroll
            for (int ks=0;ks<2;ks++)
                #pragma unroll
                for (int hl=0;hl<2;hl++)
                    A[tap][ks][hl] = *(const short8*)(W2 + (((size_t)hl*3+tap)*64 + (m0+n))*64 + ks*32 + quad*8);
        float bib[4], sc[4], bi2[4];
        #pragma unroll
        for (int reg=0;reg<4;reg++){
            int co = m0 + quad*4 + reg;
            bib[reg]=c2bB[lvl*64+co];
            sc[reg]=modscB[lvl*576+tslot*64+co];
            bi2[reg]=modbiB[lvl*576+tslot*64+co];
        }
        const float dt6 = dt/6.0f;
        const int qy0=(m0+quad*4)>>1;
        for (int nt=0; nt<4; nt++){
            float4v d = {bib[0],bib[1],bib[2],bib[3]};
            #pragma unroll
            for (int tap=0;tap<3;tap++){
                const int rr = 16*nt + n + tap;
                const unsigned* ph=&hTh[rr][0];
                #pragma unroll
                for (int ks=0;ks<2;ks++){
                    short8 bh = *(const short8*)(ph + ks*16 + quad*4);
                    d = __builtin_amdgcn_mfma_f32_16x16x32_bf16(A[tap][ks][0], bh, d, 0,0,0);
                    d = __builtin_amdgcn_mfma_f32_16x16x32_bf16(A[tap][ks][1], bh, d, 0,0,0);
                }
            }
            int p = l0 + 16*nt + n;
            int ry = 16*nt + n + 2;
            unsigned uh0=yTh[ry][qy0],   ul0=yTl[ry][qy0];
            unsigned uh1=yTh[ry][qy0+1], ul1=yTl[ry][qy0+1];
            float yev[4];
            yev[0]=bf2f(uh0)+bf2f(ul0);
            yev[1]=bf2f(uh0>>16)+bf2f(ul0>>16);
            yev[2]=bf2f(uh1)+bf2f(ul1);
            yev[3]=bf2f(uh1>>16)+bf2f(ul1>>16);
            size_t gbase=(size_t)(b*64 + m0 + quad*4)*LSEQ + p;
            #pragma unroll
            for (int reg=0;reg<4;reg++){
                float m = d[reg]*sc[reg] + bi2[reg];
                float kv = siluf(m) - 0.1f*yev[reg];
                size_t gi = gbase + (size_t)reg*LSEQ;
                if (eval==0){ kout[gi]=kv; acc[gi]=kv; }
                else if (eval<3){ kout[gi]=kv; acc[gi]+=2.0f*kv; }
                else {
                    float yn = yin[gi] + dt6*(acc[gi]+kv);
                    yout[gi]=yn;
                    esum += yn*yn;
                }
            }
        }
    }
    if (do_energy){
        for (int o=32;o>0;o>>=1) esum+=__shfl_down(esum,o,64);
        if ((tid&63)==0) red[tid>>6]=esum;
        __syncthreads();
        if (tid==0) atomicAdd(&eoutB[lvl*8+b], red[0]+red[1]+red[2]+red[3]);
    }
}

// ---------------- energy renorm (batched over levels) -----------------------
__global__ __launch_bounds__(256) void scale_kernel(
    const float* __restrict__ y, const float* __restrict__ ein,
    const float* __restrict__ eout, float* __restrict__ o)
{
    int idx = blockIdx.x*256 + threadIdx.x;
    int lb = idx>>17;   // (lvl*8+b), 131072 elems each
    float eo = eout[lb]*(1.0f/131072.0f);
    o[idx] = y[idx]*sqrtf(ein[lb]/(eo+1e-8f));
}

// ---------------- 1x1 attention, detail *= (1+a) in place -------------------
__global__ __launch_bounds__(256) void attn_kernel(
    const float* __restrict__ cur, float* __restrict__ detail,
    const float* __restrict__ a1w, const float* __restrict__ a1b,
    const float* __restrict__ a2w, const float* __restrict__ a2b)
{
    __shared__ float c[64][64];
    __shared__ float hid[16][64];
    const int tid=threadIdx.x, b=blockIdx.y, l0=blockIdx.x*64;
    for (int idx=tid; idx<4096; idx+=256){
        int ci=idx>>6, p=idx&63;
        c[ci][p]=cur[(size_t)(b*64+ci)*LSEQ+l0+p];
    }
    __syncthreads();
    for (int idx=tid; idx<1024; idx+=256){
        int h=idx>>6, p=idx&63;
        float acc=a1b[h];
        const float* W=a1w+h*64;
        for (int ci=0;ci<64;ci++) acc += W[ci]*c[ci][p];
        hid[h][p]=geluf(acc);
    }
    __syncthreads();
    for (int idx=tid; idx<4096; idx+=256){
        int co=idx>>6, p=idx&63;
        float acc=a2b[co];
        const float* W=a2w+co*16;
        #pragma unroll
        for (int h=0;h<16;h++) acc += W[h]*hid[h][p];
        float a=sigf(acc);
        size_t gi=(size_t)(b*64+co)*LSEQ+l0+p;
        detail[gi] *= (1.0f+a);
    }
}

// ---------------- gate conv + residual update -------------------------------
__global__ __launch_bounds__(256) void gate_kernel(
    const float* __restrict__ cur, const float* __restrict__ detail,
    const float* __restrict__ gwt, const float* __restrict__ gb,
    float* __restrict__ curout)
{
    __shared__ float yc[64][66];
    __shared__ float dtile[64][65];
    const int tid=threadIdx.x, b=blockIdx.y, l0=blockIdx.x*64;
    for (int idx=tid; idx<64*66; idx+=256){
        int ci=idx/66, u=idx-ci*66;
        int l=l0+u-1;
        yc[ci][u]=(l>=0 && l<LSEQ)? cur[(size_t)(b*64+ci)*LSEQ+l] : 0.f;
    }
    for (int idx=tid; idx<4096; idx+=256){
        int ci=idx>>6, p=idx&63;
        dtile[ci][p]=detail[(size_t)(b*64+ci)*LSEQ+l0+p];
    }
    __syncthreads();
    const int co=tid&63, g=tid>>6;
    const int p0=g*16;
    float a[16];
    float bb=gb[co];
    #pragma unroll
    for (int i=0;i<16;i++) a[i]=bb;
    for (int ci=0;ci<64;ci++){
        float w0=gwt[(ci*3+0)*64+co];
        float w1_=gwt[(ci*3+1)*64+co];
        float w2_=gwt[(ci*3+2)*64+co];
        float x[18];
        #pragma unroll
        for (int j=0;j<18;j++) x[j]=yc[ci][p0+j];
        #pragma unroll
        for (int i=0;i<16;i++) a[i] += w0*x[i]+w1_*x[i+1]+w2_*x[i+2];
    }
    float r[16];
    #pragma unroll
    for (int i=0;i<16;i++){
        float gt=sigf(a[i]);
        r[i]=yc[co][p0+i+1]+gt*dtile[co][p0+i];
    }
    __syncthreads();
    #pragma unroll
    for (int i=0;i<16;i++) dtile[co][p0+i]=r[i];
    __syncthreads();
    for (int idx=tid; idx<4096; idx+=256){
        int ci=idx>>6, p=idx&63;
        curout[(size_t)(b*64+ci)*LSEQ+l0+p]=dtile[ci][p];
    }
}

extern "C" void kernel_launch(void* const* d_in, const int* in_sizes, int n_in,
                              void* d_out, int out_size, void* d_ws, size_t ws_size,
                              hipStream_t stream)
{
    (void)in_sizes; (void)n_in; (void)out_size; (void)ws_size;
    const float* x       =(const float*)d_in[0];
    const float* dy_w1   =(const float*)d_in[1];
    const float* dy_b1   =(const float*)d_in[2];
    const float* dy_wg1  =(const float*)d_in[3];
    const float* dy_bg1  =(const float*)d_in[4];
    const float* dy_wg2  =(const float*)d_in[5];
    const float* dy_bg2  =(const float*)d_in[6];
    const float* ode_c1w =(const float*)d_in[7];
    const float* ode_c1b =(const float*)d_in[8];
    const float* ode_c2w =(const float*)d_in[9];
    const float* ode_c2b =(const float*)d_in[10];
    const float* ode_wt  =(const float*)d_in[11];
    const float* ode_bt  =(const float*)d_in[12];
    const float* ode_wm  =(const float*)d_in[13];
    const float* ode_bm  =(const float*)d_in[14];
    const float* ode_emb =(const float*)d_in[15];
    const float* gate_w  =(const float*)d_in[16];
    const float* gate_b  =(const float*)d_in[17];
    const float* attn1_w =(const float*)d_in[18];
    const float* attn1_b =(const float*)d_in[19];
    const float* attn2_w =(const float*)d_in[20];
    const float* attn2_b =(const float*)d_in[21];
    float* out=(float*)d_out;
    float* ws=(float*)d_ws;
    const size_t N=NTOT;
    // workspace layout (floats): 20N + ~260K ≈ 85 MB
    float* CB = ws;          // coeff[4]: A0, D1, D2, D3 (4N)
    float* PB = ws+4*N;      // y ping (4 levels) — also decomp temps T0,T1
    float* QB = ws+8*N;      // y pong (4 levels)
    float* K0B= ws+12*N;
    float* K1B= ws+16*N;
    float* SM = ws+20*N;
    float* stat_ws =SM;          // 512
    float* lo_ws   =SM+512;      // 64
    float* hi_ws   =SM+576;      // 64
    float* rowstats=SM+1024;     // 4*512*8 = 16384
    float* ts_ws   =SM+17408;    // 4*8
    float* modsc   =SM+17536;    // 4*576
    float* modbi   =SM+19840;    // 4*576
    float* ein     =SM+22144;    // 32
    float* eoutb   =SM+22176;    // 32
    short* WB      =(short*)(SM+24576);  // 393216 bf16 = 196608 floats
    float* WTG     =SM+24576+196608;     // 3*12288 (gate weights, transposed)
    float* ACCB    =out;         // d_out[0..4N) free until scale_kernel

    dim3 blk(256);

    wprep_kernel<<<768,blk,0,stream>>>(ode_c1w, ode_c2w, WB);
    for (int i=0;i<3;i++)
        wtrans_kernel<<<48,blk,0,stream>>>(gate_w+(size_t)i*12288, WTG+(size_t)i*12288);

    // ---- wavelet decomposition (3 levels, sequential) ----
    const float* cura=x;
    float* outsA[3]={PB, PB+N, CB};      // T0, T1, A0-final
    float* outsD[3]={CB+N, CB+2*N, CB+3*N};
    for (int lv=0; lv<3; lv++){
        stat_kernel<<<NROWS,blk,0,stream>>>(cura, stat_ws);
        dywan_kernel<<<1,blk,0,stream>>>(stat_ws, dy_w1,dy_b1,dy_wg1,dy_bg1,dy_wg2,dy_bg2,
                                         lo_ws, hi_ws, out+4*N);
        filt_kernel<<<dim3(8,NROWS),blk,0,stream>>>(cura, lo_ws, hi_ws, outsA[lv], outsD[lv]);
        cura=outsA[lv];
    }

    // ---- adaptive grids + modulation for all 4 levels ----
    tg_pass1<<<dim3(NROWS,4),blk,0,stream>>>(CB, rowstats);
    tg_finalize<<<4,blk,0,stream>>>(rowstats, ode_wt, ode_bt, ode_wm, ode_bm,
                                    ode_emb, ts_ws, modsc, modbi, ein, eoutb);

    // ---- RK4: 16 evals, each batched over 4 levels ----
    const float* yins[4]={CB, PB, QB, PB};
    float*       youts[4]={PB, QB, PB, QB};
    for (int step=0;step<4;step++){
        for (int ev=0;ev<4;ev++){
            const float* kp=(ev==0)?K0B:((ev==1)?K0B:((ev==2)?K1B:K0B));
            float* ko=(ev==0)?K0B:((ev==1)?K1B:((ev==2)?K0B:K0B));
            int doe=(step==3 && ev==3)?1:0;
            ode_eval_all<<<dim3(32,NB,4),blk,0,stream>>>(
                yins[step],kp,ko,ACCB,youts[step],
                WB,ode_c1b,ode_c2b,modsc,modbi,ts_ws,eoutb,step,ev,doe);
        }
    }
    scale_kernel<<<4*NTOT/256,blk,0,stream>>>(QB, ein, eoutb, out);

    // ---- reconstruction ----
    // i=2: current: out0 -> PB; detail = out slot 3 (unchanged)
    gate_kernel<<<dim3(32,NB),blk,0,stream>>>(out+0*N, out+3*N, WTG+2*12288, gate_b+2*64, PB);
    // i=1: attn modifies out slot 2 in place, then gate: PB -> QB
    attn_kernel<<<dim3(32,NB),blk,0,stream>>>(PB, out+2*N, attn1_w+1024, attn1_b+16,
                                              attn2_w+1024, attn2_b+64);
    gate_kernel<<<dim3(32,NB),blk,0,stream>>>(PB, out+2*N, WTG+1*12288, gate_b+64, QB);
    // i=0: attn modifies out slot 1 in place, then gate: QB -> out slot 0
    attn_kernel<<<dim3(32,NB),blk,0,stream>>>(QB, out+1*N, attn1_w, attn1_b,
                                              attn2_w, attn2_b);
    gate_kernel<<<dim3(32,NB),blk,0,stream>>>(QB, out+1*N, WTG, gate_b, out+0*N);
}